// Round 1
// baseline (1136.904 us; speedup 1.0000x reference)
//
#include <hip/hip_runtime.h>
#include <hip/hip_bf16.h>

#define HDIM 64
#define NGRAPH 128
#define NCLS 10
#define BN_EPS 1e-5f
#define SCAN_CHUNK 1024

// ---------------- CSR build ----------------

__global__ void count_kernel(const int* __restrict__ dst, int* __restrict__ deg, int E) {
    int e = blockIdx.x * blockDim.x + threadIdx.x;
    if (e < E) atomicAdd(&deg[dst[e]], 1);
}

__global__ void scan1_kernel(const int* __restrict__ deg, int* __restrict__ part, int N) {
    __shared__ int sh[256];
    int base = blockIdx.x * SCAN_CHUNK + threadIdx.x * 4;
    int s = 0;
#pragma unroll
    for (int i = 0; i < 4; i++) { int idx = base + i; if (idx < N) s += deg[idx]; }
    sh[threadIdx.x] = s; __syncthreads();
    for (int off = 128; off > 0; off >>= 1) {
        if (threadIdx.x < off) sh[threadIdx.x] += sh[threadIdx.x + off];
        __syncthreads();
    }
    if (threadIdx.x == 0) part[blockIdx.x] = sh[0];
}

__global__ void scan2_kernel(int* __restrict__ part, int nblk, int* __restrict__ row_ptr, int N, int E) {
    __shared__ int sh[256];
    int v = (threadIdx.x < nblk) ? part[threadIdx.x] : 0;
    sh[threadIdx.x] = v; __syncthreads();
    for (int off = 1; off < 256; off <<= 1) {
        int t = (threadIdx.x >= off) ? sh[threadIdx.x - off] : 0;
        __syncthreads();
        sh[threadIdx.x] += t;
        __syncthreads();
    }
    if (threadIdx.x < nblk) part[threadIdx.x] = sh[threadIdx.x] - v;  // exclusive
    if (threadIdx.x == 0) row_ptr[N] = E;
}

__global__ void scan3_kernel(const int* __restrict__ deg, const int* __restrict__ part,
                             int* __restrict__ row_ptr, int* __restrict__ cursor, int N) {
    __shared__ int sh[256];
    int tbase = blockIdx.x * SCAN_CHUNK + threadIdx.x * 4;
    int vals[4]; int s = 0;
#pragma unroll
    for (int i = 0; i < 4; i++) { int idx = tbase + i; vals[i] = (idx < N) ? deg[idx] : 0; s += vals[i]; }
    sh[threadIdx.x] = s; __syncthreads();
    for (int off = 1; off < 256; off <<= 1) {
        int t = (threadIdx.x >= off) ? sh[threadIdx.x - off] : 0;
        __syncthreads();
        sh[threadIdx.x] += t;
        __syncthreads();
    }
    int run = part[blockIdx.x] + sh[threadIdx.x] - s;  // exclusive prefix of this thread
#pragma unroll
    for (int i = 0; i < 4; i++) {
        int idx = tbase + i;
        if (idx < N) { row_ptr[idx] = run; cursor[idx] = run; run += vals[i]; }
    }
}

__global__ void scatter_kernel(const int* __restrict__ src, const int* __restrict__ dst,
                               int* __restrict__ cursor, int* __restrict__ col, int E) {
    int e = blockIdx.x * blockDim.x + threadIdx.x;
    if (e < E) {
        int pos = atomicAdd(&cursor[dst[e]], 1);
        col[pos] = src[e];
    }
}

// ---------------- GEMM: Y[N,64] = X[N,K] @ W[K,64], optional ReLU ----------------
// Thread-per-node; W staged in LDS, all lanes broadcast-read the same W address.

template<int K, bool RELU>
__global__ void __launch_bounds__(256) gemm_kernel(const float* __restrict__ X,
                                                   const float* __restrict__ W,
                                                   float* __restrict__ Y, int N) {
    __shared__ float Ws[K * 64];
    for (int i = threadIdx.x; i < K * 64; i += 256) Ws[i] = W[i];
    __syncthreads();
    int n = blockIdx.x * 256 + threadIdx.x;
    if (n >= N) return;
    const float4* xr = reinterpret_cast<const float4*>(X + (size_t)n * K);
    float4 acc[16];
#pragma unroll
    for (int j = 0; j < 16; j++) acc[j] = make_float4(0.f, 0.f, 0.f, 0.f);
#pragma unroll 2
    for (int k4 = 0; k4 < K / 4; k4++) {
        float4 xv = xr[k4];
#pragma unroll
        for (int s = 0; s < 4; s++) {
            float xs = (s == 0) ? xv.x : (s == 1) ? xv.y : (s == 2) ? xv.z : xv.w;
            const float4* wr = reinterpret_cast<const float4*>(Ws + (k4 * 4 + s) * 64);
#pragma unroll
            for (int j = 0; j < 16; j++) {
                float4 w = wr[j];
                acc[j].x += xs * w.x; acc[j].y += xs * w.y;
                acc[j].z += xs * w.z; acc[j].w += xs * w.w;
            }
        }
    }
    float4* yr = reinterpret_cast<float4*>(Y + (size_t)n * 64);
#pragma unroll
    for (int j = 0; j < 16; j++) {
        float4 a = acc[j];
        if (RELU) {
            a.x = fmaxf(a.x, 0.f); a.y = fmaxf(a.y, 0.f);
            a.z = fmaxf(a.z, 0.f); a.w = fmaxf(a.w, 0.f);
        }
        yr[j] = a;
    }
}

// ---------------- Aggregation (pull, CSR) + BatchNorm(eval) + ReLU ----------------
// out[n] = relu(bn(y[n] + sum_{e in CSR[n]} y[col[e]]))
// One wave per node, lane = feature. 256B coalesced row gathers, no atomics.

__global__ void agg_bn_relu_kernel(const float* __restrict__ y, const int* __restrict__ rp,
                                   const int* __restrict__ col,
                                   const float* __restrict__ gam, const float* __restrict__ bet,
                                   const float* __restrict__ mu, const float* __restrict__ var,
                                   float* __restrict__ out, int N) {
    int wid = (blockIdx.x * blockDim.x + threadIdx.x) >> 6;
    int lane = threadIdx.x & 63;
    if (wid >= N) return;
    int beg = rp[wid], end = rp[wid + 1];
    float acc = y[(size_t)wid * 64 + lane];
    int e = beg;
    for (; e + 2 <= end; e += 2) {
        int s0 = col[e], s1 = col[e + 1];
        float a0 = y[(size_t)s0 * 64 + lane];
        float a1 = y[(size_t)s1 * 64 + lane];
        acc += a0; acc += a1;
    }
    if (e < end) acc += y[(size_t)col[e] * 64 + lane];
    float sc = gam[lane] * rsqrtf(var[lane] + BN_EPS);
    float sh = bet[lane] - mu[lane] * sc;
    out[(size_t)wid * 64 + lane] = fmaxf(acc * sc + sh, 0.f);
}

// ---------------- Global mean pool (stage 1: sums + counts) ----------------

__global__ void pool_kernel(const float* __restrict__ h, const int* __restrict__ batch,
                            float* __restrict__ sums, int* __restrict__ cnts, int N) {
    int wid = (blockIdx.x * blockDim.x + threadIdx.x) >> 6;
    int lane = threadIdx.x & 63;
    int nw = (gridDim.x * blockDim.x) >> 6;
    for (int n = wid; n < N; n += nw) {
        int g = batch[n];
        atomicAdd(&sums[g * 64 + lane], h[(size_t)n * 64 + lane]);
        if (lane == 0) atomicAdd(&cnts[g], 1);
    }
}

// ---------------- MLP head + log_softmax (one 64-thread block per graph) ----------------

__global__ void head_kernel(const float* __restrict__ sums, const int* __restrict__ cnts,
                            const float* __restrict__ lin1, const float* __restrict__ lin2,
                            const float* __restrict__ b2, float* __restrict__ out) {
    int g = blockIdx.x;
    int j = threadIdx.x;  // 64 threads
    __shared__ float p[64];
    __shared__ float z1[64];
    __shared__ float z2[NCLS];
    float cnt = fmaxf((float)cnts[g], 1.f);
    p[j] = sums[g * 64 + j] / cnt;
    __syncthreads();
    float a = 0.f;
#pragma unroll
    for (int k = 0; k < 64; k++) a += p[k] * lin1[k * 64 + j];
    z1[j] = fmaxf(a, 0.f);
    __syncthreads();
    if (j < NCLS) {
        float s = b2[j];
#pragma unroll
        for (int k = 0; k < 64; k++) s += z1[k] * lin2[k * NCLS + j];
        z2[j] = s;
    }
    __syncthreads();
    if (j < NCLS) {
        float mx = -1e30f;
#pragma unroll
        for (int c = 0; c < NCLS; c++) mx = fmaxf(mx, z2[c]);
        float se = 0.f;
#pragma unroll
        for (int c = 0; c < NCLS; c++) se += expf(z2[c] - mx);
        out[g * NCLS + j] = z2[j] - mx - logf(se);
    }
}

// ---------------- launch ----------------

extern "C" void kernel_launch(void* const* d_in, const int* in_sizes, int n_in,
                              void* d_out, int out_size, void* d_ws, size_t ws_size,
                              hipStream_t stream) {
    const float* x     = (const float*)d_in[0];
    const int*   ei    = (const int*)d_in[1];
    const int*   batch = (const int*)d_in[2];
    const float* W1_0  = (const float*)d_in[3];
    const float* g0    = (const float*)d_in[4];
    const float* b0    = (const float*)d_in[5];
    const float* m0    = (const float*)d_in[6];
    const float* v0    = (const float*)d_in[7];
    const float* W2_0  = (const float*)d_in[8];
    const float* W1r   = (const float*)d_in[9];
    const float* gr    = (const float*)d_in[10];
    const float* br    = (const float*)d_in[11];
    const float* mr    = (const float*)d_in[12];
    const float* vr    = (const float*)d_in[13];
    const float* W2r   = (const float*)d_in[14];
    const float* lin1  = (const float*)d_in[15];
    const float* lin2  = (const float*)d_in[16];
    const float* b2    = (const float*)d_in[17];

    const int N = in_sizes[0] / 128;   // 100000
    const int E = in_sizes[1] / 2;     // 1000000
    const int* src = ei;
    const int* dst = ei + E;

    // ---- workspace carve (256B aligned) ----
    char* p = (char*)d_ws;
    auto alloc = [&](size_t bytes) -> char* {
        char* r = p;
        p += (bytes + 255) & ~(size_t)255;
        return r;
    };
    int*   deg       = (int*)alloc((size_t)N * 4);
    float* pool_sums = (float*)alloc((size_t)NGRAPH * 64 * 4);
    int*   pool_cnts = (int*)alloc((size_t)NGRAPH * 4);
    size_t zbytes = (size_t)((char*)pool_cnts + NGRAPH * 4 - (char*)deg);
    int*   row_ptr = (int*)alloc((size_t)(N + 1) * 4);
    int*   cursor  = (int*)alloc((size_t)N * 4);
    int*   col     = (int*)alloc((size_t)E * 4);
    int*   part    = (int*)alloc(256 * 4);
    float* hA      = (float*)alloc((size_t)N * 64 * 4);
    float* hB      = (float*)alloc((size_t)N * 64 * 4);
    (void)ws_size; (void)n_in; (void)out_size;

    hipMemsetAsync(deg, 0, zbytes, stream);

    // ---- CSR build (once per call, reused by all 4 layers) ----
    int eb = (E + 255) / 256;
    count_kernel<<<eb, 256, 0, stream>>>(dst, deg, E);
    int nblk = (N + SCAN_CHUNK - 1) / SCAN_CHUNK;
    scan1_kernel<<<nblk, 256, 0, stream>>>(deg, part, N);
    scan2_kernel<<<1, 256, 0, stream>>>(part, nblk, row_ptr, N, E);
    scan3_kernel<<<nblk, 256, 0, stream>>>(deg, part, row_ptr, cursor, N);
    scatter_kernel<<<eb, 256, 0, stream>>>(src, dst, cursor, col, E);

    int nb = (N + 255) / 256;
    int ab = (N * 64 + 255) / 256;  // wave-per-node grid

    // ---- layer 0 (F=128): y = x@W1 first, then 64-wide aggregation (linearity) ----
    gemm_kernel<128, false><<<nb, 256, 0, stream>>>(x, W1_0, hA, N);
    agg_bn_relu_kernel<<<ab, 256, 0, stream>>>(hA, row_ptr, col, g0, b0, m0, v0, hB, N);
    gemm_kernel<64, true><<<nb, 256, 0, stream>>>(hB, W2_0, hA, N);

    // ---- layers 1..3 ----
    float* cur = hA;
    float* oth = hB;
    for (int i = 0; i < 3; i++) {
        gemm_kernel<64, false><<<nb, 256, 0, stream>>>(cur, W1r + (size_t)i * 64 * 64, oth, N);
        agg_bn_relu_kernel<<<ab, 256, 0, stream>>>(oth, row_ptr, col,
                                                   gr + i * 64, br + i * 64, mr + i * 64, vr + i * 64,
                                                   cur, N);
        gemm_kernel<64, true><<<nb, 256, 0, stream>>>(cur, W2r + (size_t)i * 64 * 64, oth, N);
        float* t = cur; cur = oth; oth = t;
    }

    // ---- pool + head ----
    pool_kernel<<<1024, 256, 0, stream>>>(cur, batch, pool_sums, pool_cnts, N);
    head_kernel<<<NGRAPH, 64, 0, stream>>>(pool_sums, pool_cnts, lin1, lin2, b2, (float*)d_out);
}

// Round 3
// 915.529 us; speedup vs baseline: 1.2418x; 1.2418x over previous
//
#include <hip/hip_runtime.h>
#include <hip/hip_bf16.h>

#define HDIM 64
#define NGRAPH 128
#define NCLS 10
#define BN_EPS 1e-5f
#define SCAN_CHUNK 1024

// ---------------- CSR build ----------------

__global__ void count_kernel(const int* __restrict__ dst, int* __restrict__ deg, int E) {
    int e = blockIdx.x * blockDim.x + threadIdx.x;
    if (e < E) atomicAdd(&deg[dst[e]], 1);
}

__global__ void scan1_kernel(const int* __restrict__ deg, int* __restrict__ part, int N) {
    __shared__ int sh[256];
    int base = blockIdx.x * SCAN_CHUNK + threadIdx.x * 4;
    int s = 0;
#pragma unroll
    for (int i = 0; i < 4; i++) { int idx = base + i; if (idx < N) s += deg[idx]; }
    sh[threadIdx.x] = s; __syncthreads();
    for (int off = 128; off > 0; off >>= 1) {
        if (threadIdx.x < off) sh[threadIdx.x] += sh[threadIdx.x + off];
        __syncthreads();
    }
    if (threadIdx.x == 0) part[blockIdx.x] = sh[0];
}

__global__ void scan2_kernel(int* __restrict__ part, int nblk, int* __restrict__ row_ptr, int N, int E) {
    __shared__ int sh[256];
    int v = (threadIdx.x < nblk) ? part[threadIdx.x] : 0;
    sh[threadIdx.x] = v; __syncthreads();
    for (int off = 1; off < 256; off <<= 1) {
        int t = (threadIdx.x >= off) ? sh[threadIdx.x - off] : 0;
        __syncthreads();
        sh[threadIdx.x] += t;
        __syncthreads();
    }
    if (threadIdx.x < nblk) part[threadIdx.x] = sh[threadIdx.x] - v;  // exclusive
    if (threadIdx.x == 0) row_ptr[N] = E;
}

__global__ void scan3_kernel(const int* __restrict__ deg, const int* __restrict__ part,
                             int* __restrict__ row_ptr, int* __restrict__ cursor, int N) {
    __shared__ int sh[256];
    int tbase = blockIdx.x * SCAN_CHUNK + threadIdx.x * 4;
    int vals[4]; int s = 0;
#pragma unroll
    for (int i = 0; i < 4; i++) { int idx = tbase + i; vals[i] = (idx < N) ? deg[idx] : 0; s += vals[i]; }
    sh[threadIdx.x] = s; __syncthreads();
    for (int off = 1; off < 256; off <<= 1) {
        int t = (threadIdx.x >= off) ? sh[threadIdx.x - off] : 0;
        __syncthreads();
        sh[threadIdx.x] += t;
        __syncthreads();
    }
    int run = part[blockIdx.x] + sh[threadIdx.x] - s;  // exclusive prefix of this thread
#pragma unroll
    for (int i = 0; i < 4; i++) {
        int idx = tbase + i;
        if (idx < N) { row_ptr[idx] = run; cursor[idx] = run; run += vals[i]; }
    }
}

__global__ void scatter_kernel(const int* __restrict__ src, const int* __restrict__ dst,
                               int* __restrict__ cursor, int* __restrict__ col, int E) {
    int e = blockIdx.x * blockDim.x + threadIdx.x;
    if (e < E) {
        int pos = atomicAdd(&cursor[dst[e]], 1);
        col[pos] = src[e];
    }
}

// ---------------- GEMM: Y[N,64] = X[N,K] @ W[K,64], optional ReLU ----------------

template<int K, bool RELU>
__global__ void __launch_bounds__(256) gemm_kernel(const float* __restrict__ X,
                                                   const float* __restrict__ W,
                                                   float* __restrict__ Y, int N) {
    __shared__ float Ws[K * 64];
    for (int i = threadIdx.x; i < K * 64; i += 256) Ws[i] = W[i];
    __syncthreads();
    int n = blockIdx.x * 256 + threadIdx.x;
    if (n >= N) return;
    const float4* xr = reinterpret_cast<const float4*>(X + (size_t)n * K);
    float4 acc[16];
#pragma unroll
    for (int j = 0; j < 16; j++) acc[j] = make_float4(0.f, 0.f, 0.f, 0.f);
#pragma unroll 2
    for (int k4 = 0; k4 < K / 4; k4++) {
        float4 xv = xr[k4];
#pragma unroll
        for (int s = 0; s < 4; s++) {
            float xs = (s == 0) ? xv.x : (s == 1) ? xv.y : (s == 2) ? xv.z : xv.w;
            const float4* wr = reinterpret_cast<const float4*>(Ws + (k4 * 4 + s) * 64);
#pragma unroll
            for (int j = 0; j < 16; j++) {
                float4 w = wr[j];
                acc[j].x += xs * w.x; acc[j].y += xs * w.y;
                acc[j].z += xs * w.z; acc[j].w += xs * w.w;
            }
        }
    }
    float4* yr = reinterpret_cast<float4*>(Y + (size_t)n * 64);
#pragma unroll
    for (int j = 0; j < 16; j++) {
        float4 a = acc[j];
        if (RELU) {
            a.x = fmaxf(a.x, 0.f); a.y = fmaxf(a.y, 0.f);
            a.z = fmaxf(a.z, 0.f); a.w = fmaxf(a.w, 0.f);
        }
        yr[j] = a;
    }
}

// ---------------- Aggregation (pull, CSR) + BatchNorm(eval) + ReLU ----------------
// One wave per node, lane = feature. 4-deep unrolled gather for latency hiding.

__global__ void agg_bn_relu_kernel(const float* __restrict__ y, const int* __restrict__ rp,
                                   const int* __restrict__ col,
                                   const float* __restrict__ gam, const float* __restrict__ bet,
                                   const float* __restrict__ mu, const float* __restrict__ var,
                                   float* __restrict__ out, int N) {
    int wid = (blockIdx.x * blockDim.x + threadIdx.x) >> 6;
    int lane = threadIdx.x & 63;
    if (wid >= N) return;
    int beg = rp[wid], end = rp[wid + 1];
    float acc = y[(size_t)wid * 64 + lane];
    int e = beg;
    for (; e + 4 <= end; e += 4) {
        int s0 = col[e], s1 = col[e + 1], s2 = col[e + 2], s3 = col[e + 3];
        float a0 = y[(size_t)s0 * 64 + lane];
        float a1 = y[(size_t)s1 * 64 + lane];
        float a2 = y[(size_t)s2 * 64 + lane];
        float a3 = y[(size_t)s3 * 64 + lane];
        acc += a0 + a1 + a2 + a3;
    }
    for (; e < end; ++e) acc += y[(size_t)col[e] * 64 + lane];
    float sc = gam[lane] * rsqrtf(var[lane] + BN_EPS);
    float sh = bet[lane] - mu[lane] * sc;
    out[(size_t)wid * 64 + lane] = fmaxf(acc * sc + sh, 0.f);
}

// ---------------- Global mean pool, stage A: LDS-privatized partials ----------------
// Each block owns a private [128 graphs x 64 feats] LDS accumulator + per-graph count.
// No global atomics. LDS atomicAdd lane->bank map is conflict-free (bank = lane%32).

__global__ void __launch_bounds__(256) pool_partial_kernel(const float* __restrict__ h,
                                                           const int* __restrict__ batch,
                                                           float* __restrict__ partial,
                                                           int* __restrict__ pcnt, int N) {
    __shared__ float ls[NGRAPH * 64];
    __shared__ int lc[NGRAPH];
    for (int i = threadIdx.x; i < NGRAPH * 64; i += 256) ls[i] = 0.f;
    if (threadIdx.x < NGRAPH) lc[threadIdx.x] = 0;
    __syncthreads();
    int lane = threadIdx.x & 63;
    int gwave = blockIdx.x * 4 + (threadIdx.x >> 6);
    int nwaves = gridDim.x * 4;
#pragma unroll 4
    for (int n = gwave; n < N; n += nwaves) {
        int g = batch[n];
        atomicAdd(&ls[g * 64 + lane], h[(size_t)n * 64 + lane]);
        if (lane == 0) atomicAdd(&lc[g], 1);
    }
    __syncthreads();
    for (int i = threadIdx.x; i < NGRAPH * 64; i += 256)
        partial[(size_t)blockIdx.x * NGRAPH * 64 + i] = ls[i];
    if (threadIdx.x < NGRAPH) pcnt[blockIdx.x * NGRAPH + threadIdx.x] = lc[threadIdx.x];
}

// ---------------- Partial-reduce + MLP head + log_softmax (block per graph) ----------------

__global__ void head_kernel(const float* __restrict__ partial, const int* __restrict__ pcnt, int P,
                            const float* __restrict__ lin1, const float* __restrict__ lin2,
                            const float* __restrict__ b2, float* __restrict__ out) {
    int g = blockIdx.x;
    int j = threadIdx.x;  // 64 threads
    __shared__ float p[64];
    __shared__ float z1[64];
    __shared__ float z2[NCLS];
    __shared__ int csh[64];
    float s = 0.f;
    for (int b = 0; b < P; b++) s += partial[(size_t)b * NGRAPH * 64 + g * 64 + j];
    int c = 0;
    for (int b = j; b < P; b += 64) c += pcnt[b * NGRAPH + g];
    csh[j] = c; __syncthreads();
    if (j == 0) { int t = 0; for (int k = 0; k < 64; k++) t += csh[k]; csh[0] = t; }
    __syncthreads();
    float cnt = fmaxf((float)csh[0], 1.f);
    p[j] = s / cnt;
    __syncthreads();
    float a = 0.f;
#pragma unroll
    for (int k = 0; k < 64; k++) a += p[k] * lin1[k * 64 + j];
    z1[j] = fmaxf(a, 0.f);
    __syncthreads();
    if (j < NCLS) {
        float t = b2[j];
#pragma unroll
        for (int k = 0; k < 64; k++) t += z1[k] * lin2[k * NCLS + j];
        z2[j] = t;
    }
    __syncthreads();
    if (j < NCLS) {
        float mx = -1e30f;
#pragma unroll
        for (int c2 = 0; c2 < NCLS; c2++) mx = fmaxf(mx, z2[c2]);
        float se = 0.f;
#pragma unroll
        for (int c2 = 0; c2 < NCLS; c2++) se += expf(z2[c2] - mx);
        out[g * NCLS + j] = z2[j] - mx - logf(se);
    }
}

// ---------------- launch ----------------

extern "C" void kernel_launch(void* const* d_in, const int* in_sizes, int n_in,
                              void* d_out, int out_size, void* d_ws, size_t ws_size,
                              hipStream_t stream) {
    const float* x     = (const float*)d_in[0];
    const int*   ei    = (const int*)d_in[1];
    const int*   batch = (const int*)d_in[2];
    const float* W1_0  = (const float*)d_in[3];
    const float* g0    = (const float*)d_in[4];
    const float* b0    = (const float*)d_in[5];
    const float* m0    = (const float*)d_in[6];
    const float* v0    = (const float*)d_in[7];
    const float* W2_0  = (const float*)d_in[8];
    const float* W1r   = (const float*)d_in[9];
    const float* gr    = (const float*)d_in[10];
    const float* br    = (const float*)d_in[11];
    const float* mr    = (const float*)d_in[12];
    const float* vr    = (const float*)d_in[13];
    const float* W2r   = (const float*)d_in[14];
    const float* lin1  = (const float*)d_in[15];
    const float* lin2  = (const float*)d_in[16];
    const float* b2    = (const float*)d_in[17];

    const int N = in_sizes[0] / 128;   // 100000
    const int E = in_sizes[1] / 2;     // 1000000
    const int* src = ei;
    const int* dst = ei + E;

    // ---- workspace carve (256B aligned) ----
    char* p = (char*)d_ws;
    auto alloc = [&](size_t bytes) -> char* {
        char* r = p;
        p += (bytes + 255) & ~(size_t)255;
        return r;
    };
    int*   deg     = (int*)alloc((size_t)N * 4);
    int*   row_ptr = (int*)alloc((size_t)(N + 1) * 4);
    int*   cursor  = (int*)alloc((size_t)N * 4);
    int*   col     = (int*)alloc((size_t)E * 4);
    int*   part    = (int*)alloc(256 * 4);
    float* hA      = (float*)alloc((size_t)N * 64 * 4);
    float* hB      = (float*)alloc((size_t)N * 64 * 4);
    // pool partials: adapt block count to whatever workspace remains (>=1 always correct)
    size_t used = (size_t)(p - (char*)d_ws);
    size_t per_block = ((size_t)NGRAPH * 64 * 4) + ((size_t)NGRAPH * 4) + 512;
    size_t remain = (ws_size > used) ? (ws_size - used) : 0;
    int P = (int)(remain / per_block);
    if (P > 256) P = 256;
    if (P < 1) P = 1;
    float* partial = (float*)alloc((size_t)P * NGRAPH * 64 * 4);
    int*   pcnt    = (int*)alloc((size_t)P * NGRAPH * 4);
    (void)n_in; (void)out_size;

    hipMemsetAsync(deg, 0, (size_t)N * 4, stream);

    // ---- CSR build (once per call, reused by all 4 layers) ----
    int eb = (E + 255) / 256;
    count_kernel<<<eb, 256, 0, stream>>>(dst, deg, E);
    int nblk = (N + SCAN_CHUNK - 1) / SCAN_CHUNK;
    scan1_kernel<<<nblk, 256, 0, stream>>>(deg, part, N);
    scan2_kernel<<<1, 256, 0, stream>>>(part, nblk, row_ptr, N, E);
    scan3_kernel<<<nblk, 256, 0, stream>>>(deg, part, row_ptr, cursor, N);
    scatter_kernel<<<eb, 256, 0, stream>>>(src, dst, cursor, col, E);

    int nb = (N + 255) / 256;
    int ab = (N * 64 + 255) / 256;  // wave-per-node grid

    // ---- layer 0 (F=128): y = x@W1 first, then 64-wide aggregation (linearity) ----
    gemm_kernel<128, false><<<nb, 256, 0, stream>>>(x, W1_0, hA, N);
    agg_bn_relu_kernel<<<ab, 256, 0, stream>>>(hA, row_ptr, col, g0, b0, m0, v0, hB, N);
    gemm_kernel<64, true><<<nb, 256, 0, stream>>>(hB, W2_0, hA, N);

    // ---- layers 1..3 ----
    float* cur = hA;
    float* oth = hB;
    for (int i = 0; i < 3; i++) {
        gemm_kernel<64, false><<<nb, 256, 0, stream>>>(cur, W1r + (size_t)i * 64 * 64, oth, N);
        agg_bn_relu_kernel<<<ab, 256, 0, stream>>>(oth, row_ptr, col,
                                                   gr + i * 64, br + i * 64, mr + i * 64, vr + i * 64,
                                                   cur, N);
        gemm_kernel<64, true><<<nb, 256, 0, stream>>>(cur, W2r + (size_t)i * 64 * 64, oth, N);
        float* t = cur; cur = oth; oth = t;
    }

    // ---- pool (LDS-privatized partials) + head (reduce + MLP + log_softmax) ----
    pool_partial_kernel<<<P, 256, 0, stream>>>(cur, batch, partial, pcnt, N);
    head_kernel<<<NGRAPH, 64, 0, stream>>>(partial, pcnt, P, lin1, lin2, b2, (float*)d_out);
}

// Round 4
// 694.510 us; speedup vs baseline: 1.6370x; 1.3182x over previous
//
#include <hip/hip_runtime.h>
#include <hip/hip_bf16.h>

#define HDIM 64
#define NGRAPH 128
#define NCLS 10
#define BN_EPS 1e-5f
#define SCAN_CHUNK 1024

// ---------------- CSR build ----------------

__global__ void count_kernel(const int* __restrict__ dst, int* __restrict__ deg, int E) {
    int e = blockIdx.x * blockDim.x + threadIdx.x;
    if (e < E) atomicAdd(&deg[dst[e]], 1);
}

__global__ void scan1_kernel(const int* __restrict__ deg, int* __restrict__ part, int N) {
    __shared__ int sh[256];
    int base = blockIdx.x * SCAN_CHUNK + threadIdx.x * 4;
    int s = 0;
#pragma unroll
    for (int i = 0; i < 4; i++) { int idx = base + i; if (idx < N) s += deg[idx]; }
    sh[threadIdx.x] = s; __syncthreads();
    for (int off = 128; off > 0; off >>= 1) {
        if (threadIdx.x < off) sh[threadIdx.x] += sh[threadIdx.x + off];
        __syncthreads();
    }
    if (threadIdx.x == 0) part[blockIdx.x] = sh[0];
}

__global__ void scan2_kernel(int* __restrict__ part, int nblk, int* __restrict__ row_ptr, int N, int E) {
    __shared__ int sh[256];
    int v = (threadIdx.x < nblk) ? part[threadIdx.x] : 0;
    sh[threadIdx.x] = v; __syncthreads();
    for (int off = 1; off < 256; off <<= 1) {
        int t = (threadIdx.x >= off) ? sh[threadIdx.x - off] : 0;
        __syncthreads();
        sh[threadIdx.x] += t;
        __syncthreads();
    }
    if (threadIdx.x < nblk) part[threadIdx.x] = sh[threadIdx.x] - v;  // exclusive
    if (threadIdx.x == 0) row_ptr[N] = E;
}

__global__ void scan3_kernel(const int* __restrict__ deg, const int* __restrict__ part,
                             int* __restrict__ row_ptr, int* __restrict__ cursor, int N) {
    __shared__ int sh[256];
    int tbase = blockIdx.x * SCAN_CHUNK + threadIdx.x * 4;
    int vals[4]; int s = 0;
#pragma unroll
    for (int i = 0; i < 4; i++) { int idx = tbase + i; vals[i] = (idx < N) ? deg[idx] : 0; s += vals[i]; }
    sh[threadIdx.x] = s; __syncthreads();
    for (int off = 1; off < 256; off <<= 1) {
        int t = (threadIdx.x >= off) ? sh[threadIdx.x - off] : 0;
        __syncthreads();
        sh[threadIdx.x] += t;
        __syncthreads();
    }
    int run = part[blockIdx.x] + sh[threadIdx.x] - s;  // exclusive prefix of this thread
#pragma unroll
    for (int i = 0; i < 4; i++) {
        int idx = tbase + i;
        if (idx < N) { row_ptr[idx] = run; cursor[idx] = run; run += vals[i]; }
    }
}

__global__ void scatter_kernel(const int* __restrict__ src, const int* __restrict__ dst,
                               int* __restrict__ cursor, int* __restrict__ col, int E) {
    int e = blockIdx.x * blockDim.x + threadIdx.x;
    if (e < E) {
        int pos = atomicAdd(&cursor[dst[e]], 1);
        col[pos] = src[e];
    }
}

// ---------------- Tiled GEMM: Y[N,64] = X[N,K] @ W[K,64], optional ReLU ----------------
// 64-node x 64-output tile per 256-thread block; each thread computes a 4x4 sub-tile.
// Xs staged TRANSPOSED [k][n] with lane==row during staging (2-way LDS write conflicts
// only = free); inner loop is 2 ds_read_b128 + 16 FMA per k-step (VALU-bound).

template<int K, bool RELU>
__global__ void __launch_bounds__(256) gemm_tiled_kernel(const float* __restrict__ X,
                                                         const float* __restrict__ W,
                                                         float* __restrict__ Y, int N) {
    __shared__ float Xs[K * 64];   // [k][n]
    __shared__ float Ws[K * 64];   // [k][j]
    const int tid = threadIdx.x;
    const int base = blockIdx.x * 64;

    // stage W: coalesced float4 copy
    {
        const float4* Wv = reinterpret_cast<const float4*>(W);
        float4* Wsv = reinterpret_cast<float4*>(Ws);
        for (int i = tid; i < K * 16; i += 256) Wsv[i] = Wv[i];
    }
    // stage X transposed: i = c4*64 + r, r fast so a wave writes 64 consecutive r
    for (int i = tid; i < 16 * K; i += 256) {
        int r = i & 63;
        int c4 = i >> 6;
        int n = base + r;
        float4 v = make_float4(0.f, 0.f, 0.f, 0.f);
        if (n < N) v = *reinterpret_cast<const float4*>(X + (size_t)n * K + c4 * 4);
        Xs[(c4 * 4 + 0) * 64 + r] = v.x;
        Xs[(c4 * 4 + 1) * 64 + r] = v.y;
        Xs[(c4 * 4 + 2) * 64 + r] = v.z;
        Xs[(c4 * 4 + 3) * 64 + r] = v.w;
    }
    __syncthreads();

    const int ti = tid >> 4;   // node group 0..15
    const int tj = tid & 15;   // output group 0..15
    float4 acc[4];
#pragma unroll
    for (int a = 0; a < 4; a++) acc[a] = make_float4(0.f, 0.f, 0.f, 0.f);

#pragma unroll 4
    for (int k = 0; k < K; k++) {
        float4 xv = *reinterpret_cast<const float4*>(&Xs[k * 64 + 4 * ti]);
        float4 wv = *reinterpret_cast<const float4*>(&Ws[k * 64 + 4 * tj]);
        acc[0].x += xv.x * wv.x; acc[0].y += xv.x * wv.y; acc[0].z += xv.x * wv.z; acc[0].w += xv.x * wv.w;
        acc[1].x += xv.y * wv.x; acc[1].y += xv.y * wv.y; acc[1].z += xv.y * wv.z; acc[1].w += xv.y * wv.w;
        acc[2].x += xv.z * wv.x; acc[2].y += xv.z * wv.y; acc[2].z += xv.z * wv.z; acc[2].w += xv.z * wv.w;
        acc[3].x += xv.w * wv.x; acc[3].y += xv.w * wv.y; acc[3].z += xv.w * wv.z; acc[3].w += xv.w * wv.w;
    }

#pragma unroll
    for (int a = 0; a < 4; a++) {
        int n = base + 4 * ti + a;
        if (n < N) {
            float4 o = acc[a];
            if (RELU) {
                o.x = fmaxf(o.x, 0.f); o.y = fmaxf(o.y, 0.f);
                o.z = fmaxf(o.z, 0.f); o.w = fmaxf(o.w, 0.f);
            }
            *reinterpret_cast<float4*>(Y + (size_t)n * 64 + 4 * tj) = o;
        }
    }
}

// ---------------- Aggregation (pull, CSR) + BatchNorm(eval) + ReLU ----------------
// One wave per node, lane = feature. 4-deep unrolled gather for latency hiding.

__global__ void agg_bn_relu_kernel(const float* __restrict__ y, const int* __restrict__ rp,
                                   const int* __restrict__ col,
                                   const float* __restrict__ gam, const float* __restrict__ bet,
                                   const float* __restrict__ mu, const float* __restrict__ var,
                                   float* __restrict__ out, int N) {
    int wid = (blockIdx.x * blockDim.x + threadIdx.x) >> 6;
    int lane = threadIdx.x & 63;
    if (wid >= N) return;
    int beg = rp[wid], end = rp[wid + 1];
    float acc = y[(size_t)wid * 64 + lane];
    int e = beg;
    for (; e + 4 <= end; e += 4) {
        int s0 = col[e], s1 = col[e + 1], s2 = col[e + 2], s3 = col[e + 3];
        float a0 = y[(size_t)s0 * 64 + lane];
        float a1 = y[(size_t)s1 * 64 + lane];
        float a2 = y[(size_t)s2 * 64 + lane];
        float a3 = y[(size_t)s3 * 64 + lane];
        acc += a0 + a1 + a2 + a3;
    }
    for (; e < end; ++e) acc += y[(size_t)col[e] * 64 + lane];
    float sc = gam[lane] * rsqrtf(var[lane] + BN_EPS);
    float sh = bet[lane] - mu[lane] * sc;
    out[(size_t)wid * 64 + lane] = fmaxf(acc * sc + sh, 0.f);
}

// ---------------- Global mean pool, stage A: LDS-privatized partials ----------------

__global__ void __launch_bounds__(256) pool_partial_kernel(const float* __restrict__ h,
                                                           const int* __restrict__ batch,
                                                           float* __restrict__ partial,
                                                           int* __restrict__ pcnt, int N) {
    __shared__ float ls[NGRAPH * 64];
    __shared__ int lc[NGRAPH];
    for (int i = threadIdx.x; i < NGRAPH * 64; i += 256) ls[i] = 0.f;
    if (threadIdx.x < NGRAPH) lc[threadIdx.x] = 0;
    __syncthreads();
    int lane = threadIdx.x & 63;
    int gwave = blockIdx.x * 4 + (threadIdx.x >> 6);
    int nwaves = gridDim.x * 4;
#pragma unroll 4
    for (int n = gwave; n < N; n += nwaves) {
        int g = batch[n];
        atomicAdd(&ls[g * 64 + lane], h[(size_t)n * 64 + lane]);
        if (lane == 0) atomicAdd(&lc[g], 1);
    }
    __syncthreads();
    for (int i = threadIdx.x; i < NGRAPH * 64; i += 256)
        partial[(size_t)blockIdx.x * NGRAPH * 64 + i] = ls[i];
    if (threadIdx.x < NGRAPH) pcnt[blockIdx.x * NGRAPH + threadIdx.x] = lc[threadIdx.x];
}

// ---------------- Partial-reduce + MLP head + log_softmax (block per graph) ----------------

__global__ void head_kernel(const float* __restrict__ partial, const int* __restrict__ pcnt, int P,
                            const float* __restrict__ lin1, const float* __restrict__ lin2,
                            const float* __restrict__ b2, float* __restrict__ out) {
    int g = blockIdx.x;
    int j = threadIdx.x;  // 64 threads
    __shared__ float p[64];
    __shared__ float z1[64];
    __shared__ float z2[NCLS];
    __shared__ int csh[64];
    float s = 0.f;
    for (int b = 0; b < P; b++) s += partial[(size_t)b * NGRAPH * 64 + g * 64 + j];
    int c = 0;
    for (int b = j; b < P; b += 64) c += pcnt[b * NGRAPH + g];
    csh[j] = c; __syncthreads();
    if (j == 0) { int t = 0; for (int k = 0; k < 64; k++) t += csh[k]; csh[0] = t; }
    __syncthreads();
    float cnt = fmaxf((float)csh[0], 1.f);
    p[j] = s / cnt;
    __syncthreads();
    float a = 0.f;
#pragma unroll
    for (int k = 0; k < 64; k++) a += p[k] * lin1[k * 64 + j];
    z1[j] = fmaxf(a, 0.f);
    __syncthreads();
    if (j < NCLS) {
        float t = b2[j];
#pragma unroll
        for (int k = 0; k < 64; k++) t += z1[k] * lin2[k * NCLS + j];
        z2[j] = t;
    }
    __syncthreads();
    if (j < NCLS) {
        float mx = -1e30f;
#pragma unroll
        for (int c2 = 0; c2 < NCLS; c2++) mx = fmaxf(mx, z2[c2]);
        float se = 0.f;
#pragma unroll
        for (int c2 = 0; c2 < NCLS; c2++) se += expf(z2[c2] - mx);
        out[g * NCLS + j] = z2[j] - mx - logf(se);
    }
}

// ---------------- launch ----------------

extern "C" void kernel_launch(void* const* d_in, const int* in_sizes, int n_in,
                              void* d_out, int out_size, void* d_ws, size_t ws_size,
                              hipStream_t stream) {
    const float* x     = (const float*)d_in[0];
    const int*   ei    = (const int*)d_in[1];
    const int*   batch = (const int*)d_in[2];
    const float* W1_0  = (const float*)d_in[3];
    const float* g0    = (const float*)d_in[4];
    const float* b0    = (const float*)d_in[5];
    const float* m0    = (const float*)d_in[6];
    const float* v0    = (const float*)d_in[7];
    const float* W2_0  = (const float*)d_in[8];
    const float* W1r   = (const float*)d_in[9];
    const float* gr    = (const float*)d_in[10];
    const float* br    = (const float*)d_in[11];
    const float* mr    = (const float*)d_in[12];
    const float* vr    = (const float*)d_in[13];
    const float* W2r   = (const float*)d_in[14];
    const float* lin1  = (const float*)d_in[15];
    const float* lin2  = (const float*)d_in[16];
    const float* b2    = (const float*)d_in[17];

    const int N = in_sizes[0] / 128;   // 100000
    const int E = in_sizes[1] / 2;     // 1000000
    const int* src = ei;
    const int* dst = ei + E;

    // ---- workspace carve (256B aligned) ----
    char* p = (char*)d_ws;
    auto alloc = [&](size_t bytes) -> char* {
        char* r = p;
        p += (bytes + 255) & ~(size_t)255;
        return r;
    };
    int*   deg     = (int*)alloc((size_t)N * 4);
    int*   row_ptr = (int*)alloc((size_t)(N + 1) * 4);
    int*   cursor  = (int*)alloc((size_t)N * 4);
    int*   col     = (int*)alloc((size_t)E * 4);
    int*   part    = (int*)alloc(256 * 4);
    float* hA      = (float*)alloc((size_t)N * 64 * 4);
    float* hB      = (float*)alloc((size_t)N * 64 * 4);
    size_t used = (size_t)(p - (char*)d_ws);
    size_t per_block = ((size_t)NGRAPH * 64 * 4) + ((size_t)NGRAPH * 4) + 512;
    size_t remain = (ws_size > used) ? (ws_size - used) : 0;
    int P = (int)(remain / per_block);
    if (P > 256) P = 256;
    if (P < 1) P = 1;
    float* partial = (float*)alloc((size_t)P * NGRAPH * 64 * 4);
    int*   pcnt    = (int*)alloc((size_t)P * NGRAPH * 4);
    (void)n_in; (void)out_size;

    hipMemsetAsync(deg, 0, (size_t)N * 4, stream);

    // ---- CSR build (once per call, reused by all 4 layers) ----
    int eb = (E + 255) / 256;
    count_kernel<<<eb, 256, 0, stream>>>(dst, deg, E);
    int nblk = (N + SCAN_CHUNK - 1) / SCAN_CHUNK;
    scan1_kernel<<<nblk, 256, 0, stream>>>(deg, part, N);
    scan2_kernel<<<1, 256, 0, stream>>>(part, nblk, row_ptr, N, E);
    scan3_kernel<<<nblk, 256, 0, stream>>>(deg, part, row_ptr, cursor, N);
    scatter_kernel<<<eb, 256, 0, stream>>>(src, dst, cursor, col, E);

    int mb = (N + 63) / 64;          // tiled-GEMM grid
    int ab = (N * 64 + 255) / 256;   // wave-per-node grid

    // ---- layer 0 (F=128): y = x@W1 first, then 64-wide aggregation (linearity) ----
    gemm_tiled_kernel<128, false><<<mb, 256, 0, stream>>>(x, W1_0, hA, N);
    agg_bn_relu_kernel<<<ab, 256, 0, stream>>>(hA, row_ptr, col, g0, b0, m0, v0, hB, N);
    gemm_tiled_kernel<64, true><<<mb, 256, 0, stream>>>(hB, W2_0, hA, N);

    // ---- layers 1..3 ----
    float* cur = hA;
    float* oth = hB;
    for (int i = 0; i < 3; i++) {
        gemm_tiled_kernel<64, false><<<mb, 256, 0, stream>>>(cur, W1r + (size_t)i * 64 * 64, oth, N);
        agg_bn_relu_kernel<<<ab, 256, 0, stream>>>(oth, row_ptr, col,
                                                   gr + i * 64, br + i * 64, mr + i * 64, vr + i * 64,
                                                   cur, N);
        gemm_tiled_kernel<64, true><<<mb, 256, 0, stream>>>(cur, W2r + (size_t)i * 64 * 64, oth, N);
        float* t = cur; cur = oth; oth = t;
    }

    // ---- pool (LDS-privatized partials) + head (reduce + MLP + log_softmax) ----
    pool_partial_kernel<<<P, 256, 0, stream>>>(cur, batch, partial, pcnt, N);
    head_kernel<<<NGRAPH, 64, 0, stream>>>(partial, pcnt, P, lin1, lin2, b2, (float*)d_out);
}

// Round 5
// 693.729 us; speedup vs baseline: 1.6388x; 1.0011x over previous
//
#include <hip/hip_runtime.h>
#include <hip/hip_bf16.h>

#define HDIM 64
#define NGRAPH 128
#define NCLS 10
#define BN_EPS 1e-5f
#define SCAN_CHUNK 1024

// ---------------- CSR build ----------------

__global__ void count_kernel(const int* __restrict__ dst, int* __restrict__ deg, int E) {
    int e = blockIdx.x * blockDim.x + threadIdx.x;
    if (e < E) atomicAdd(&deg[dst[e]], 1);
}

__global__ void scan1_kernel(const int* __restrict__ deg, int* __restrict__ part, int N) {
    __shared__ int sh[256];
    int base = blockIdx.x * SCAN_CHUNK + threadIdx.x * 4;
    int s = 0;
#pragma unroll
    for (int i = 0; i < 4; i++) { int idx = base + i; if (idx < N) s += deg[idx]; }
    sh[threadIdx.x] = s; __syncthreads();
    for (int off = 128; off > 0; off >>= 1) {
        if (threadIdx.x < off) sh[threadIdx.x] += sh[threadIdx.x + off];
        __syncthreads();
    }
    if (threadIdx.x == 0) part[blockIdx.x] = sh[0];
}

__global__ void scan2_kernel(int* __restrict__ part, int nblk, int* __restrict__ row_ptr, int N, int E) {
    __shared__ int sh[256];
    int v = (threadIdx.x < nblk) ? part[threadIdx.x] : 0;
    sh[threadIdx.x] = v; __syncthreads();
    for (int off = 1; off < 256; off <<= 1) {
        int t = (threadIdx.x >= off) ? sh[threadIdx.x - off] : 0;
        __syncthreads();
        sh[threadIdx.x] += t;
        __syncthreads();
    }
    if (threadIdx.x < nblk) part[threadIdx.x] = sh[threadIdx.x] - v;  // exclusive
    if (threadIdx.x == 0) row_ptr[N] = E;
}

__global__ void scan3_kernel(const int* __restrict__ deg, const int* __restrict__ part,
                             int* __restrict__ row_ptr, int* __restrict__ cursor, int N) {
    __shared__ int sh[256];
    int tbase = blockIdx.x * SCAN_CHUNK + threadIdx.x * 4;
    int vals[4]; int s = 0;
#pragma unroll
    for (int i = 0; i < 4; i++) { int idx = tbase + i; vals[i] = (idx < N) ? deg[idx] : 0; s += vals[i]; }
    sh[threadIdx.x] = s; __syncthreads();
    for (int off = 1; off < 256; off <<= 1) {
        int t = (threadIdx.x >= off) ? sh[threadIdx.x - off] : 0;
        __syncthreads();
        sh[threadIdx.x] += t;
        __syncthreads();
    }
    int run = part[blockIdx.x] + sh[threadIdx.x] - s;  // exclusive prefix of this thread
#pragma unroll
    for (int i = 0; i < 4; i++) {
        int idx = tbase + i;
        if (idx < N) { row_ptr[idx] = run; cursor[idx] = run; run += vals[i]; }
    }
}

__global__ void scatter_kernel(const int* __restrict__ src, const int* __restrict__ dst,
                               int* __restrict__ cursor, int* __restrict__ col, int E) {
    int e = blockIdx.x * blockDim.x + threadIdx.x;
    if (e < E) {
        int pos = atomicAdd(&cursor[dst[e]], 1);
        col[pos] = src[e];
    }
}

// ---------------- Tiled GEMM: Y[N,64] = X[N,K] @ W[K,64], optional ReLU ----------------
// 64-node x 64-output tile per 256-thread block; each thread computes a 4x4 sub-tile.

template<int K, bool RELU>
__global__ void __launch_bounds__(256) gemm_tiled_kernel(const float* __restrict__ X,
                                                         const float* __restrict__ W,
                                                         float* __restrict__ Y, int N) {
    __shared__ float Xs[K * 64];   // [k][n]
    __shared__ float Ws[K * 64];   // [k][j]
    const int tid = threadIdx.x;
    const int base = blockIdx.x * 64;

    {
        const float4* Wv = reinterpret_cast<const float4*>(W);
        float4* Wsv = reinterpret_cast<float4*>(Ws);
        for (int i = tid; i < K * 16; i += 256) Wsv[i] = Wv[i];
    }
    for (int i = tid; i < 16 * K; i += 256) {
        int r = i & 63;
        int c4 = i >> 6;
        int n = base + r;
        float4 v = make_float4(0.f, 0.f, 0.f, 0.f);
        if (n < N) v = *reinterpret_cast<const float4*>(X + (size_t)n * K + c4 * 4);
        Xs[(c4 * 4 + 0) * 64 + r] = v.x;
        Xs[(c4 * 4 + 1) * 64 + r] = v.y;
        Xs[(c4 * 4 + 2) * 64 + r] = v.z;
        Xs[(c4 * 4 + 3) * 64 + r] = v.w;
    }
    __syncthreads();

    const int ti = tid >> 4;
    const int tj = tid & 15;
    float4 acc[4];
#pragma unroll
    for (int a = 0; a < 4; a++) acc[a] = make_float4(0.f, 0.f, 0.f, 0.f);

#pragma unroll 4
    for (int k = 0; k < K; k++) {
        float4 xv = *reinterpret_cast<const float4*>(&Xs[k * 64 + 4 * ti]);
        float4 wv = *reinterpret_cast<const float4*>(&Ws[k * 64 + 4 * tj]);
        acc[0].x += xv.x * wv.x; acc[0].y += xv.x * wv.y; acc[0].z += xv.x * wv.z; acc[0].w += xv.x * wv.w;
        acc[1].x += xv.y * wv.x; acc[1].y += xv.y * wv.y; acc[1].z += xv.y * wv.z; acc[1].w += xv.y * wv.w;
        acc[2].x += xv.z * wv.x; acc[2].y += xv.z * wv.y; acc[2].z += xv.z * wv.z; acc[2].w += xv.z * wv.w;
        acc[3].x += xv.w * wv.x; acc[3].y += xv.w * wv.y; acc[3].z += xv.w * wv.z; acc[3].w += xv.w * wv.w;
    }

#pragma unroll
    for (int a = 0; a < 4; a++) {
        int n = base + 4 * ti + a;
        if (n < N) {
            float4 o = acc[a];
            if (RELU) {
                o.x = fmaxf(o.x, 0.f); o.y = fmaxf(o.y, 0.f);
                o.z = fmaxf(o.z, 0.f); o.w = fmaxf(o.w, 0.f);
            }
            *reinterpret_cast<float4*>(Y + (size_t)n * 64 + 4 * tj) = o;
        }
    }
}

// ---------------- Fused GEMM pair: Y = relu(H @ W2) @ W1n ----------------
// Stage 1 tile in regs -> ReLU -> LDS (reuse Hs, n-major: float4 writes + broadcast
// reads, both bank-conflict-free) -> stage 2 tile. 48KB LDS -> 3 blocks/CU.

__global__ void __launch_bounds__(256) gemm_pair_kernel(const float* __restrict__ H,
                                                        const float* __restrict__ W2,
                                                        const float* __restrict__ W1n,
                                                        float* __restrict__ Y, int N) {
    __shared__ float Hs[64 * 64];   // stage1: [k][n]; reused as Z [n][j] for stage2
    __shared__ float W2s[64 * 64];  // [k][j]
    __shared__ float W1s[64 * 64];  // [k][j]
    const int tid = threadIdx.x;
    const int base = blockIdx.x * 64;

    {
        const float4* a = reinterpret_cast<const float4*>(W2);
        const float4* c = reinterpret_cast<const float4*>(W1n);
        float4* b = reinterpret_cast<float4*>(W2s);
        float4* d = reinterpret_cast<float4*>(W1s);
        for (int i = tid; i < 1024; i += 256) { b[i] = a[i]; d[i] = c[i]; }
    }
    for (int i = tid; i < 1024; i += 256) {
        int r = i & 63;
        int c4 = i >> 6;
        int n = base + r;
        float4 v = make_float4(0.f, 0.f, 0.f, 0.f);
        if (n < N) v = *reinterpret_cast<const float4*>(H + (size_t)n * 64 + c4 * 4);
        Hs[(c4 * 4 + 0) * 64 + r] = v.x;
        Hs[(c4 * 4 + 1) * 64 + r] = v.y;
        Hs[(c4 * 4 + 2) * 64 + r] = v.z;
        Hs[(c4 * 4 + 3) * 64 + r] = v.w;
    }
    __syncthreads();

    const int ti = tid >> 4;
    const int tj = tid & 15;
    float4 acc[4];
#pragma unroll
    for (int a = 0; a < 4; a++) acc[a] = make_float4(0.f, 0.f, 0.f, 0.f);

#pragma unroll 4
    for (int k = 0; k < 64; k++) {
        float4 xv = *reinterpret_cast<const float4*>(&Hs[k * 64 + 4 * ti]);
        float4 wv = *reinterpret_cast<const float4*>(&W2s[k * 64 + 4 * tj]);
        acc[0].x += xv.x * wv.x; acc[0].y += xv.x * wv.y; acc[0].z += xv.x * wv.z; acc[0].w += xv.x * wv.w;
        acc[1].x += xv.y * wv.x; acc[1].y += xv.y * wv.y; acc[1].z += xv.y * wv.z; acc[1].w += xv.y * wv.w;
        acc[2].x += xv.z * wv.x; acc[2].y += xv.z * wv.y; acc[2].z += xv.z * wv.z; acc[2].w += xv.z * wv.w;
        acc[3].x += xv.w * wv.x; acc[3].y += xv.w * wv.y; acc[3].z += xv.w * wv.z; acc[3].w += xv.w * wv.w;
    }
    __syncthreads();   // Hs fully consumed by all waves

    // write relu(Z) into Hs n-major: Z[4ti+a][4tj..4tj+3] (float4, conflict-free)
#pragma unroll
    for (int a = 0; a < 4; a++) {
        float4 o = acc[a];
        o.x = fmaxf(o.x, 0.f); o.y = fmaxf(o.y, 0.f);
        o.z = fmaxf(o.z, 0.f); o.w = fmaxf(o.w, 0.f);
        *reinterpret_cast<float4*>(&Hs[(4 * ti + a) * 64 + 4 * tj]) = o;
    }
    __syncthreads();

    float4 acc2[4];
#pragma unroll
    for (int a = 0; a < 4; a++) acc2[a] = make_float4(0.f, 0.f, 0.f, 0.f);

#pragma unroll 4
    for (int k = 0; k < 64; k++) {
        // Z[n][k] scalar reads, identical addr across tj -> LDS broadcast (free)
        float z0 = Hs[(4 * ti + 0) * 64 + k];
        float z1 = Hs[(4 * ti + 1) * 64 + k];
        float z2 = Hs[(4 * ti + 2) * 64 + k];
        float z3 = Hs[(4 * ti + 3) * 64 + k];
        float4 wv = *reinterpret_cast<const float4*>(&W1s[k * 64 + 4 * tj]);
        acc2[0].x += z0 * wv.x; acc2[0].y += z0 * wv.y; acc2[0].z += z0 * wv.z; acc2[0].w += z0 * wv.w;
        acc2[1].x += z1 * wv.x; acc2[1].y += z1 * wv.y; acc2[1].z += z1 * wv.z; acc2[1].w += z1 * wv.w;
        acc2[2].x += z2 * wv.x; acc2[2].y += z2 * wv.y; acc2[2].z += z2 * wv.z; acc2[2].w += z2 * wv.w;
        acc2[3].x += z3 * wv.x; acc2[3].y += z3 * wv.y; acc2[3].z += z3 * wv.z; acc2[3].w += z3 * wv.w;
    }

#pragma unroll
    for (int a = 0; a < 4; a++) {
        int n = base + 4 * ti + a;
        if (n < N) *reinterpret_cast<float4*>(Y + (size_t)n * 64 + 4 * tj) = acc2[a];
    }
}

// ---------------- Aggregation (pull, CSR) + BatchNorm(eval) + ReLU ----------------

__global__ void agg_bn_relu_kernel(const float* __restrict__ y, const int* __restrict__ rp,
                                   const int* __restrict__ col,
                                   const float* __restrict__ gam, const float* __restrict__ bet,
                                   const float* __restrict__ mu, const float* __restrict__ var,
                                   float* __restrict__ out, int N) {
    int wid = (blockIdx.x * blockDim.x + threadIdx.x) >> 6;
    int lane = threadIdx.x & 63;
    if (wid >= N) return;
    int beg = rp[wid], end = rp[wid + 1];
    float acc = y[(size_t)wid * 64 + lane];
    int e = beg;
    for (; e + 4 <= end; e += 4) {
        int s0 = col[e], s1 = col[e + 1], s2 = col[e + 2], s3 = col[e + 3];
        float a0 = y[(size_t)s0 * 64 + lane];
        float a1 = y[(size_t)s1 * 64 + lane];
        float a2 = y[(size_t)s2 * 64 + lane];
        float a3 = y[(size_t)s3 * 64 + lane];
        acc += a0 + a1 + a2 + a3;
    }
    for (; e < end; ++e) acc += y[(size_t)col[e] * 64 + lane];
    float sc = gam[lane] * rsqrtf(var[lane] + BN_EPS);
    float sh = bet[lane] - mu[lane] * sc;
    out[(size_t)wid * 64 + lane] = fmaxf(acc * sc + sh, 0.f);
}

// ---------------- Global mean pool, stage A: LDS-privatized partials ----------------

__global__ void __launch_bounds__(256) pool_partial_kernel(const float* __restrict__ h,
                                                           const int* __restrict__ batch,
                                                           float* __restrict__ partial,
                                                           int* __restrict__ pcnt, int N) {
    __shared__ float ls[NGRAPH * 64];
    __shared__ int lc[NGRAPH];
    for (int i = threadIdx.x; i < NGRAPH * 64; i += 256) ls[i] = 0.f;
    if (threadIdx.x < NGRAPH) lc[threadIdx.x] = 0;
    __syncthreads();
    int lane = threadIdx.x & 63;
    int gwave = blockIdx.x * 4 + (threadIdx.x >> 6);
    int nwaves = gridDim.x * 4;
#pragma unroll 4
    for (int n = gwave; n < N; n += nwaves) {
        int g = batch[n];
        atomicAdd(&ls[g * 64 + lane], h[(size_t)n * 64 + lane]);
        if (lane == 0) atomicAdd(&lc[g], 1);
    }
    __syncthreads();
    for (int i = threadIdx.x; i < NGRAPH * 64; i += 256)
        partial[(size_t)blockIdx.x * NGRAPH * 64 + i] = ls[i];
    if (threadIdx.x < NGRAPH) pcnt[blockIdx.x * NGRAPH + threadIdx.x] = lc[threadIdx.x];
}

// ---------------- Partial-reduce + MLP head + log_softmax (block per graph) ----------------

__global__ void head_kernel(const float* __restrict__ partial, const int* __restrict__ pcnt, int P,
                            const float* __restrict__ lin1, const float* __restrict__ lin2,
                            const float* __restrict__ b2, float* __restrict__ out) {
    int g = blockIdx.x;
    int j = threadIdx.x;  // 64 threads
    __shared__ float p[64];
    __shared__ float z1[64];
    __shared__ float z2[NCLS];
    __shared__ int csh[64];
    float s = 0.f;
    for (int b = 0; b < P; b++) s += partial[(size_t)b * NGRAPH * 64 + g * 64 + j];
    int c = 0;
    for (int b = j; b < P; b += 64) c += pcnt[b * NGRAPH + g];
    csh[j] = c; __syncthreads();
    if (j == 0) { int t = 0; for (int k = 0; k < 64; k++) t += csh[k]; csh[0] = t; }
    __syncthreads();
    float cnt = fmaxf((float)csh[0], 1.f);
    p[j] = s / cnt;
    __syncthreads();
    float a = 0.f;
#pragma unroll
    for (int k = 0; k < 64; k++) a += p[k] * lin1[k * 64 + j];
    z1[j] = fmaxf(a, 0.f);
    __syncthreads();
    if (j < NCLS) {
        float t = b2[j];
#pragma unroll
        for (int k = 0; k < 64; k++) t += z1[k] * lin2[k * NCLS + j];
        z2[j] = t;
    }
    __syncthreads();
    if (j < NCLS) {
        float mx = -1e30f;
#pragma unroll
        for (int c2 = 0; c2 < NCLS; c2++) mx = fmaxf(mx, z2[c2]);
        float se = 0.f;
#pragma unroll
        for (int c2 = 0; c2 < NCLS; c2++) se += expf(z2[c2] - mx);
        out[g * NCLS + j] = z2[j] - mx - logf(se);
    }
}

// ---------------- launch ----------------

extern "C" void kernel_launch(void* const* d_in, const int* in_sizes, int n_in,
                              void* d_out, int out_size, void* d_ws, size_t ws_size,
                              hipStream_t stream) {
    const float* x     = (const float*)d_in[0];
    const int*   ei    = (const int*)d_in[1];
    const int*   batch = (const int*)d_in[2];
    const float* W1_0  = (const float*)d_in[3];
    const float* g0    = (const float*)d_in[4];
    const float* b0    = (const float*)d_in[5];
    const float* m0    = (const float*)d_in[6];
    const float* v0    = (const float*)d_in[7];
    const float* W2_0  = (const float*)d_in[8];
    const float* W1r   = (const float*)d_in[9];
    const float* gr    = (const float*)d_in[10];
    const float* br    = (const float*)d_in[11];
    const float* mr    = (const float*)d_in[12];
    const float* vr    = (const float*)d_in[13];
    const float* W2r   = (const float*)d_in[14];
    const float* lin1  = (const float*)d_in[15];
    const float* lin2  = (const float*)d_in[16];
    const float* b2    = (const float*)d_in[17];

    const int N = in_sizes[0] / 128;   // 100000
    const int E = in_sizes[1] / 2;     // 1000000
    const int* src = ei;
    const int* dst = ei + E;

    // ---- workspace carve (256B aligned) ----
    char* p = (char*)d_ws;
    auto alloc = [&](size_t bytes) -> char* {
        char* r = p;
        p += (bytes + 255) & ~(size_t)255;
        return r;
    };
    int*   deg     = (int*)alloc((size_t)N * 4);
    int*   row_ptr = (int*)alloc((size_t)(N + 1) * 4);
    int*   cursor  = (int*)alloc((size_t)N * 4);
    int*   col     = (int*)alloc((size_t)E * 4);
    int*   part    = (int*)alloc(256 * 4);
    float* hA      = (float*)alloc((size_t)N * 64 * 4);
    float* hB      = (float*)alloc((size_t)N * 64 * 4);
    size_t used = (size_t)(p - (char*)d_ws);
    size_t per_block = ((size_t)NGRAPH * 64 * 4) + ((size_t)NGRAPH * 4) + 512;
    size_t remain = (ws_size > used) ? (ws_size - used) : 0;
    int P = (int)(remain / per_block);
    if (P > 256) P = 256;
    if (P < 1) P = 1;
    float* partial = (float*)alloc((size_t)P * NGRAPH * 64 * 4);
    int*   pcnt    = (int*)alloc((size_t)P * NGRAPH * 4);
    (void)n_in; (void)out_size;

    hipMemsetAsync(deg, 0, (size_t)N * 4, stream);

    // ---- CSR build (once per call, reused by all 4 layers) ----
    int eb = (E + 255) / 256;
    count_kernel<<<eb, 256, 0, stream>>>(dst, deg, E);
    int nblk = (N + SCAN_CHUNK - 1) / SCAN_CHUNK;
    scan1_kernel<<<nblk, 256, 0, stream>>>(deg, part, N);
    scan2_kernel<<<1, 256, 0, stream>>>(part, nblk, row_ptr, N, E);
    scan3_kernel<<<nblk, 256, 0, stream>>>(deg, part, row_ptr, cursor, N);
    scatter_kernel<<<eb, 256, 0, stream>>>(src, dst, cursor, col, E);

    int mb = (N + 63) / 64;
    int ab = (N * 64 + 255) / 256;

    // ---- layer 0: y = x@W1_0, agg+bn+relu ----
    gemm_tiled_kernel<128, false><<<mb, 256, 0, stream>>>(x, W1_0, hA, N);
    agg_bn_relu_kernel<<<ab, 256, 0, stream>>>(hA, row_ptr, col, g0, b0, m0, v0, hB, N);

    // ---- fused pairs: relu(h@W2_i) @ W1_{i+1}, then agg+bn+relu ----
    gemm_pair_kernel<<<mb, 256, 0, stream>>>(hB, W2_0, W1r, hA, N);
    agg_bn_relu_kernel<<<ab, 256, 0, stream>>>(hA, row_ptr, col, gr, br, mr, vr, hB, N);

    gemm_pair_kernel<<<mb, 256, 0, stream>>>(hB, W2r, W1r + 4096, hA, N);
    agg_bn_relu_kernel<<<ab, 256, 0, stream>>>(hA, row_ptr, col, gr + 64, br + 64, mr + 64, vr + 64, hB, N);

    gemm_pair_kernel<<<mb, 256, 0, stream>>>(hB, W2r + 4096, W1r + 8192, hA, N);
    agg_bn_relu_kernel<<<ab, 256, 0, stream>>>(hA, row_ptr, col, gr + 128, br + 128, mr + 128, vr + 128, hB, N);

    // ---- last layer: relu(h@W2_3) ----
    gemm_tiled_kernel<64, true><<<mb, 256, 0, stream>>>(hB, W2r + 8192, hA, N);

    // ---- pool (LDS-privatized partials) + head ----
    pool_partial_kernel<<<P, 256, 0, stream>>>(hA, batch, partial, pcnt, N);
    head_kernel<<<NGRAPH, 64, 0, stream>>>(partial, pcnt, P, lin1, lin2, b2, (float*)d_out);
}

// Round 6
// 690.112 us; speedup vs baseline: 1.6474x; 1.0052x over previous
//
#include <hip/hip_runtime.h>
#include <hip/hip_bf16.h>

#define HDIM 64
#define NGRAPH 128
#define NCLS 10
#define BN_EPS 1e-5f
#define SCAN_CHUNK 1024

// ---------------- CSR build ----------------

__global__ void count_kernel(const int* __restrict__ dst, int* __restrict__ deg, int E) {
    int e = blockIdx.x * blockDim.x + threadIdx.x;
    if (e < E) atomicAdd(&deg[dst[e]], 1);
}

__global__ void scan1_kernel(const int* __restrict__ deg, int* __restrict__ part, int N) {
    __shared__ int sh[256];
    int base = blockIdx.x * SCAN_CHUNK + threadIdx.x * 4;
    int s = 0;
#pragma unroll
    for (int i = 0; i < 4; i++) { int idx = base + i; if (idx < N) s += deg[idx]; }
    sh[threadIdx.x] = s; __syncthreads();
    for (int off = 128; off > 0; off >>= 1) {
        if (threadIdx.x < off) sh[threadIdx.x] += sh[threadIdx.x + off];
        __syncthreads();
    }
    if (threadIdx.x == 0) part[blockIdx.x] = sh[0];
}

__global__ void scan2_kernel(int* __restrict__ part, int nblk, int* __restrict__ row_ptr, int N, int E) {
    __shared__ int sh[256];
    int v = (threadIdx.x < nblk) ? part[threadIdx.x] : 0;
    sh[threadIdx.x] = v; __syncthreads();
    for (int off = 1; off < 256; off <<= 1) {
        int t = (threadIdx.x >= off) ? sh[threadIdx.x - off] : 0;
        __syncthreads();
        sh[threadIdx.x] += t;
        __syncthreads();
    }
    if (threadIdx.x < nblk) part[threadIdx.x] = sh[threadIdx.x] - v;  // exclusive
    if (threadIdx.x == 0) row_ptr[N] = E;
}

__global__ void scan3_kernel(const int* __restrict__ deg, const int* __restrict__ part,
                             int* __restrict__ row_ptr, int* __restrict__ cursor, int N) {
    __shared__ int sh[256];
    int tbase = blockIdx.x * SCAN_CHUNK + threadIdx.x * 4;
    int vals[4]; int s = 0;
#pragma unroll
    for (int i = 0; i < 4; i++) { int idx = tbase + i; vals[i] = (idx < N) ? deg[idx] : 0; s += vals[i]; }
    sh[threadIdx.x] = s; __syncthreads();
    for (int off = 1; off < 256; off <<= 1) {
        int t = (threadIdx.x >= off) ? sh[threadIdx.x - off] : 0;
        __syncthreads();
        sh[threadIdx.x] += t;
        __syncthreads();
    }
    int run = part[blockIdx.x] + sh[threadIdx.x] - s;  // exclusive prefix of this thread
#pragma unroll
    for (int i = 0; i < 4; i++) {
        int idx = tbase + i;
        if (idx < N) { row_ptr[idx] = run; cursor[idx] = run; run += vals[i]; }
    }
}

// ---------------- Fused: scatter (blocks [0,eb)) + layer-0 GEMM (blocks [eb,eb+mb)) ----
// Scatter is latency/write-bound (VALUBusy 0.3%); the K=128 GEMM is VALU-bound and
// independent of the CSR build -> co-schedule them in one dispatch so the machine
// overlaps them. GEMM stages K in two 64-halves: 32KB LDS -> 5 blocks/CU so scatter
// blocks keep high occupancy.

__global__ void __launch_bounds__(256) fused_scatter_gemm0_kernel(
        const int* __restrict__ src, const int* __restrict__ dst,
        int* __restrict__ cursor, int* __restrict__ col, int E, int eb,
        const float* __restrict__ X, const float* __restrict__ W,
        float* __restrict__ Y, int N) {
    __shared__ float Xs[64 * 64];   // [k][n] for current K-half
    __shared__ float Ws[64 * 64];   // [k][j] for current K-half

    if ((int)blockIdx.x < eb) {
        int e = blockIdx.x * 256 + threadIdx.x;
        if (e < E) {
            int pos = atomicAdd(&cursor[dst[e]], 1);
            col[pos] = src[e];
        }
        return;
    }

    const int tid = threadIdx.x;
    const int base = (blockIdx.x - eb) * 64;
    const int ti = tid >> 4;
    const int tj = tid & 15;
    float4 acc[4];
#pragma unroll
    for (int a = 0; a < 4; a++) acc[a] = make_float4(0.f, 0.f, 0.f, 0.f);

    for (int kh = 0; kh < 2; kh++) {
        // stage W half: rows kh*64..kh*64+63
        {
            const float4* Wv = reinterpret_cast<const float4*>(W + kh * 64 * 64);
            float4* Wsv = reinterpret_cast<float4*>(Ws);
            for (int i = tid; i < 1024; i += 256) Wsv[i] = Wv[i];
        }
        // stage X half transposed: Xs[k][n] = X[n][kh*64 + k]
        for (int i = tid; i < 1024; i += 256) {
            int r = i & 63;
            int c4 = i >> 6;
            int n = base + r;
            float4 v = make_float4(0.f, 0.f, 0.f, 0.f);
            if (n < N) v = *reinterpret_cast<const float4*>(X + (size_t)n * 128 + kh * 64 + c4 * 4);
            Xs[(c4 * 4 + 0) * 64 + r] = v.x;
            Xs[(c4 * 4 + 1) * 64 + r] = v.y;
            Xs[(c4 * 4 + 2) * 64 + r] = v.z;
            Xs[(c4 * 4 + 3) * 64 + r] = v.w;
        }
        __syncthreads();

#pragma unroll 4
        for (int k = 0; k < 64; k++) {
            float4 xv = *reinterpret_cast<const float4*>(&Xs[k * 64 + 4 * ti]);
            float4 wv = *reinterpret_cast<const float4*>(&Ws[k * 64 + 4 * tj]);
            acc[0].x += xv.x * wv.x; acc[0].y += xv.x * wv.y; acc[0].z += xv.x * wv.z; acc[0].w += xv.x * wv.w;
            acc[1].x += xv.y * wv.x; acc[1].y += xv.y * wv.y; acc[1].z += xv.y * wv.z; acc[1].w += xv.y * wv.w;
            acc[2].x += xv.z * wv.x; acc[2].y += xv.z * wv.y; acc[2].z += xv.z * wv.z; acc[2].w += xv.z * wv.w;
            acc[3].x += xv.w * wv.x; acc[3].y += xv.w * wv.y; acc[3].z += xv.w * wv.z; acc[3].w += xv.w * wv.w;
        }
        __syncthreads();   // before restaging next K-half
    }

#pragma unroll
    for (int a = 0; a < 4; a++) {
        int n = base + 4 * ti + a;
        if (n < N) *reinterpret_cast<float4*>(Y + (size_t)n * 64 + 4 * tj) = acc[a];
    }
}

// ---------------- Tiled GEMM: Y[N,64] = X[N,64] @ W[64,64], optional ReLU ----------------

template<bool RELU>
__global__ void __launch_bounds__(256) gemm_tiled_kernel(const float* __restrict__ X,
                                                         const float* __restrict__ W,
                                                         float* __restrict__ Y, int N) {
    __shared__ float Xs[64 * 64];   // [k][n]
    __shared__ float Ws[64 * 64];   // [k][j]
    const int tid = threadIdx.x;
    const int base = blockIdx.x * 64;

    {
        const float4* Wv = reinterpret_cast<const float4*>(W);
        float4* Wsv = reinterpret_cast<float4*>(Ws);
        for (int i = tid; i < 1024; i += 256) Wsv[i] = Wv[i];
    }
    for (int i = tid; i < 1024; i += 256) {
        int r = i & 63;
        int c4 = i >> 6;
        int n = base + r;
        float4 v = make_float4(0.f, 0.f, 0.f, 0.f);
        if (n < N) v = *reinterpret_cast<const float4*>(X + (size_t)n * 64 + c4 * 4);
        Xs[(c4 * 4 + 0) * 64 + r] = v.x;
        Xs[(c4 * 4 + 1) * 64 + r] = v.y;
        Xs[(c4 * 4 + 2) * 64 + r] = v.z;
        Xs[(c4 * 4 + 3) * 64 + r] = v.w;
    }
    __syncthreads();

    const int ti = tid >> 4;
    const int tj = tid & 15;
    float4 acc[4];
#pragma unroll
    for (int a = 0; a < 4; a++) acc[a] = make_float4(0.f, 0.f, 0.f, 0.f);

#pragma unroll 4
    for (int k = 0; k < 64; k++) {
        float4 xv = *reinterpret_cast<const float4*>(&Xs[k * 64 + 4 * ti]);
        float4 wv = *reinterpret_cast<const float4*>(&Ws[k * 64 + 4 * tj]);
        acc[0].x += xv.x * wv.x; acc[0].y += xv.x * wv.y; acc[0].z += xv.x * wv.z; acc[0].w += xv.x * wv.w;
        acc[1].x += xv.y * wv.x; acc[1].y += xv.y * wv.y; acc[1].z += xv.y * wv.z; acc[1].w += xv.y * wv.w;
        acc[2].x += xv.z * wv.x; acc[2].y += xv.z * wv.y; acc[2].z += xv.z * wv.z; acc[2].w += xv.z * wv.w;
        acc[3].x += xv.w * wv.x; acc[3].y += xv.w * wv.y; acc[3].z += xv.w * wv.z; acc[3].w += xv.w * wv.w;
    }

#pragma unroll
    for (int a = 0; a < 4; a++) {
        int n = base + 4 * ti + a;
        if (n < N) {
            float4 o = acc[a];
            if (RELU) {
                o.x = fmaxf(o.x, 0.f); o.y = fmaxf(o.y, 0.f);
                o.z = fmaxf(o.z, 0.f); o.w = fmaxf(o.w, 0.f);
            }
            *reinterpret_cast<float4*>(Y + (size_t)n * 64 + 4 * tj) = o;
        }
    }
}

// ---------------- Fused GEMM pair: Y = relu(H @ W2) @ W1n ----------------

__global__ void __launch_bounds__(256) gemm_pair_kernel(const float* __restrict__ H,
                                                        const float* __restrict__ W2,
                                                        const float* __restrict__ W1n,
                                                        float* __restrict__ Y, int N) {
    __shared__ float Hs[64 * 64];   // stage1: [k][n]; reused as Z [n][j] for stage2
    __shared__ float W2s[64 * 64];  // [k][j]
    __shared__ float W1s[64 * 64];  // [k][j]
    const int tid = threadIdx.x;
    const int base = blockIdx.x * 64;

    {
        const float4* a = reinterpret_cast<const float4*>(W2);
        const float4* c = reinterpret_cast<const float4*>(W1n);
        float4* b = reinterpret_cast<float4*>(W2s);
        float4* d = reinterpret_cast<float4*>(W1s);
        for (int i = tid; i < 1024; i += 256) { b[i] = a[i]; d[i] = c[i]; }
    }
    for (int i = tid; i < 1024; i += 256) {
        int r = i & 63;
        int c4 = i >> 6;
        int n = base + r;
        float4 v = make_float4(0.f, 0.f, 0.f, 0.f);
        if (n < N) v = *reinterpret_cast<const float4*>(H + (size_t)n * 64 + c4 * 4);
        Hs[(c4 * 4 + 0) * 64 + r] = v.x;
        Hs[(c4 * 4 + 1) * 64 + r] = v.y;
        Hs[(c4 * 4 + 2) * 64 + r] = v.z;
        Hs[(c4 * 4 + 3) * 64 + r] = v.w;
    }
    __syncthreads();

    const int ti = tid >> 4;
    const int tj = tid & 15;
    float4 acc[4];
#pragma unroll
    for (int a = 0; a < 4; a++) acc[a] = make_float4(0.f, 0.f, 0.f, 0.f);

#pragma unroll 4
    for (int k = 0; k < 64; k++) {
        float4 xv = *reinterpret_cast<const float4*>(&Hs[k * 64 + 4 * ti]);
        float4 wv = *reinterpret_cast<const float4*>(&W2s[k * 64 + 4 * tj]);
        acc[0].x += xv.x * wv.x; acc[0].y += xv.x * wv.y; acc[0].z += xv.x * wv.z; acc[0].w += xv.x * wv.w;
        acc[1].x += xv.y * wv.x; acc[1].y += xv.y * wv.y; acc[1].z += xv.y * wv.z; acc[1].w += xv.y * wv.w;
        acc[2].x += xv.z * wv.x; acc[2].y += xv.z * wv.y; acc[2].z += xv.z * wv.z; acc[2].w += xv.z * wv.w;
        acc[3].x += xv.w * wv.x; acc[3].y += xv.w * wv.y; acc[3].z += xv.w * wv.z; acc[3].w += xv.w * wv.w;
    }
    __syncthreads();

#pragma unroll
    for (int a = 0; a < 4; a++) {
        float4 o = acc[a];
        o.x = fmaxf(o.x, 0.f); o.y = fmaxf(o.y, 0.f);
        o.z = fmaxf(o.z, 0.f); o.w = fmaxf(o.w, 0.f);
        *reinterpret_cast<float4*>(&Hs[(4 * ti + a) * 64 + 4 * tj]) = o;
    }
    __syncthreads();

    float4 acc2[4];
#pragma unroll
    for (int a = 0; a < 4; a++) acc2[a] = make_float4(0.f, 0.f, 0.f, 0.f);

#pragma unroll 4
    for (int k = 0; k < 64; k++) {
        float z0 = Hs[(4 * ti + 0) * 64 + k];
        float z1 = Hs[(4 * ti + 1) * 64 + k];
        float z2 = Hs[(4 * ti + 2) * 64 + k];
        float z3 = Hs[(4 * ti + 3) * 64 + k];
        float4 wv = *reinterpret_cast<const float4*>(&W1s[k * 64 + 4 * tj]);
        acc2[0].x += z0 * wv.x; acc2[0].y += z0 * wv.y; acc2[0].z += z0 * wv.z; acc2[0].w += z0 * wv.w;
        acc2[1].x += z1 * wv.x; acc2[1].y += z1 * wv.y; acc2[1].z += z1 * wv.z; acc2[1].w += z1 * wv.w;
        acc2[2].x += z2 * wv.x; acc2[2].y += z2 * wv.y; acc2[2].z += z2 * wv.z; acc2[2].w += z2 * wv.w;
        acc2[3].x += z3 * wv.x; acc2[3].y += z3 * wv.y; acc2[3].z += z3 * wv.z; acc2[3].w += z3 * wv.w;
    }

#pragma unroll
    for (int a = 0; a < 4; a++) {
        int n = base + 4 * ti + a;
        if (n < N) *reinterpret_cast<float4*>(Y + (size_t)n * 64 + 4 * tj) = acc2[a];
    }
}

// ---------------- Aggregation (pull, CSR) + BatchNorm(eval) + ReLU ----------------

__global__ void agg_bn_relu_kernel(const float* __restrict__ y, const int* __restrict__ rp,
                                   const int* __restrict__ col,
                                   const float* __restrict__ gam, const float* __restrict__ bet,
                                   const float* __restrict__ mu, const float* __restrict__ var,
                                   float* __restrict__ out, int N) {
    int wid = (blockIdx.x * blockDim.x + threadIdx.x) >> 6;
    int lane = threadIdx.x & 63;
    if (wid >= N) return;
    int beg = rp[wid], end = rp[wid + 1];
    float acc = y[(size_t)wid * 64 + lane];
    int e = beg;
    for (; e + 4 <= end; e += 4) {
        int s0 = col[e], s1 = col[e + 1], s2 = col[e + 2], s3 = col[e + 3];
        float a0 = y[(size_t)s0 * 64 + lane];
        float a1 = y[(size_t)s1 * 64 + lane];
        float a2 = y[(size_t)s2 * 64 + lane];
        float a3 = y[(size_t)s3 * 64 + lane];
        acc += a0 + a1 + a2 + a3;
    }
    for (; e < end; ++e) acc += y[(size_t)col[e] * 64 + lane];
    float sc = gam[lane] * rsqrtf(var[lane] + BN_EPS);
    float sh = bet[lane] - mu[lane] * sc;
    out[(size_t)wid * 64 + lane] = fmaxf(acc * sc + sh, 0.f);
}

// ---------------- Global mean pool, stage A: LDS-privatized partials ----------------

__global__ void __launch_bounds__(256) pool_partial_kernel(const float* __restrict__ h,
                                                           const int* __restrict__ batch,
                                                           float* __restrict__ partial,
                                                           int* __restrict__ pcnt, int N) {
    __shared__ float ls[NGRAPH * 64];
    __shared__ int lc[NGRAPH];
    for (int i = threadIdx.x; i < NGRAPH * 64; i += 256) ls[i] = 0.f;
    if (threadIdx.x < NGRAPH) lc[threadIdx.x] = 0;
    __syncthreads();
    int lane = threadIdx.x & 63;
    int gwave = blockIdx.x * 4 + (threadIdx.x >> 6);
    int nwaves = gridDim.x * 4;
#pragma unroll 4
    for (int n = gwave; n < N; n += nwaves) {
        int g = batch[n];
        atomicAdd(&ls[g * 64 + lane], h[(size_t)n * 64 + lane]);
        if (lane == 0) atomicAdd(&lc[g], 1);
    }
    __syncthreads();
    for (int i = threadIdx.x; i < NGRAPH * 64; i += 256)
        partial[(size_t)blockIdx.x * NGRAPH * 64 + i] = ls[i];
    if (threadIdx.x < NGRAPH) pcnt[blockIdx.x * NGRAPH + threadIdx.x] = lc[threadIdx.x];
}

// ---------------- Partial-reduce + MLP head + log_softmax (block per graph) ----------------

__global__ void head_kernel(const float* __restrict__ partial, const int* __restrict__ pcnt, int P,
                            const float* __restrict__ lin1, const float* __restrict__ lin2,
                            const float* __restrict__ b2, float* __restrict__ out) {
    int g = blockIdx.x;
    int j = threadIdx.x;  // 64 threads
    __shared__ float p[64];
    __shared__ float z1[64];
    __shared__ float z2[NCLS];
    __shared__ int csh[64];
    float s = 0.f;
    for (int b = 0; b < P; b++) s += partial[(size_t)b * NGRAPH * 64 + g * 64 + j];
    int c = 0;
    for (int b = j; b < P; b += 64) c += pcnt[b * NGRAPH + g];
    csh[j] = c; __syncthreads();
    if (j == 0) { int t = 0; for (int k = 0; k < 64; k++) t += csh[k]; csh[0] = t; }
    __syncthreads();
    float cnt = fmaxf((float)csh[0], 1.f);
    p[j] = s / cnt;
    __syncthreads();
    float a = 0.f;
#pragma unroll
    for (int k = 0; k < 64; k++) a += p[k] * lin1[k * 64 + j];
    z1[j] = fmaxf(a, 0.f);
    __syncthreads();
    if (j < NCLS) {
        float t = b2[j];
#pragma unroll
        for (int k = 0; k < 64; k++) t += z1[k] * lin2[k * NCLS + j];
        z2[j] = t;
    }
    __syncthreads();
    if (j < NCLS) {
        float mx = -1e30f;
#pragma unroll
        for (int c2 = 0; c2 < NCLS; c2++) mx = fmaxf(mx, z2[c2]);
        float se = 0.f;
#pragma unroll
        for (int c2 = 0; c2 < NCLS; c2++) se += expf(z2[c2] - mx);
        out[g * NCLS + j] = z2[j] - mx - logf(se);
    }
}

// ---------------- launch ----------------

extern "C" void kernel_launch(void* const* d_in, const int* in_sizes, int n_in,
                              void* d_out, int out_size, void* d_ws, size_t ws_size,
                              hipStream_t stream) {
    const float* x     = (const float*)d_in[0];
    const int*   ei    = (const int*)d_in[1];
    const int*   batch = (const int*)d_in[2];
    const float* W1_0  = (const float*)d_in[3];
    const float* g0    = (const float*)d_in[4];
    const float* b0    = (const float*)d_in[5];
    const float* m0    = (const float*)d_in[6];
    const float* v0    = (const float*)d_in[7];
    const float* W2_0  = (const float*)d_in[8];
    const float* W1r   = (const float*)d_in[9];
    const float* gr    = (const float*)d_in[10];
    const float* br    = (const float*)d_in[11];
    const float* mr    = (const float*)d_in[12];
    const float* vr    = (const float*)d_in[13];
    const float* W2r   = (const float*)d_in[14];
    const float* lin1  = (const float*)d_in[15];
    const float* lin2  = (const float*)d_in[16];
    const float* b2    = (const float*)d_in[17];

    const int N = in_sizes[0] / 128;   // 100000
    const int E = in_sizes[1] / 2;     // 1000000
    const int* src = ei;
    const int* dst = ei + E;

    // ---- workspace carve (256B aligned) ----
    char* p = (char*)d_ws;
    auto alloc = [&](size_t bytes) -> char* {
        char* r = p;
        p += (bytes + 255) & ~(size_t)255;
        return r;
    };
    int*   deg     = (int*)alloc((size_t)N * 4);
    int*   row_ptr = (int*)alloc((size_t)(N + 1) * 4);
    int*   cursor  = (int*)alloc((size_t)N * 4);
    int*   col     = (int*)alloc((size_t)E * 4);
    int*   part    = (int*)alloc(256 * 4);
    float* hA      = (float*)alloc((size_t)N * 64 * 4);
    float* hB      = (float*)alloc((size_t)N * 64 * 4);
    size_t used = (size_t)(p - (char*)d_ws);
    size_t per_block = ((size_t)NGRAPH * 64 * 4) + ((size_t)NGRAPH * 4) + 512;
    size_t remain = (ws_size > used) ? (ws_size - used) : 0;
    int P = (int)(remain / per_block);
    if (P > 256) P = 256;
    if (P < 1) P = 1;
    float* partial = (float*)alloc((size_t)P * NGRAPH * 64 * 4);
    int*   pcnt    = (int*)alloc((size_t)P * NGRAPH * 4);
    (void)n_in; (void)out_size;

    hipMemsetAsync(deg, 0, (size_t)N * 4, stream);

    // ---- CSR build ----
    int eb = (E + 255) / 256;
    count_kernel<<<eb, 256, 0, stream>>>(dst, deg, E);
    int nblk = (N + SCAN_CHUNK - 1) / SCAN_CHUNK;
    scan1_kernel<<<nblk, 256, 0, stream>>>(deg, part, N);
    scan2_kernel<<<1, 256, 0, stream>>>(part, nblk, row_ptr, N, E);
    scan3_kernel<<<nblk, 256, 0, stream>>>(deg, part, row_ptr, cursor, N);

    int mb = (N + 63) / 64;
    int ab = (N * 64 + 255) / 256;

    // ---- fused: CSR scatter || layer-0 GEMM (independent work, one dispatch) ----
    fused_scatter_gemm0_kernel<<<eb + mb, 256, 0, stream>>>(src, dst, cursor, col, E, eb,
                                                            x, W1_0, hA, N);
    agg_bn_relu_kernel<<<ab, 256, 0, stream>>>(hA, row_ptr, col, g0, b0, m0, v0, hB, N);

    // ---- fused pairs: relu(h@W2_i) @ W1_{i+1}, then agg+bn+relu ----
    gemm_pair_kernel<<<mb, 256, 0, stream>>>(hB, W2_0, W1r, hA, N);
    agg_bn_relu_kernel<<<ab, 256, 0, stream>>>(hA, row_ptr, col, gr, br, mr, vr, hB, N);

    gemm_pair_kernel<<<mb, 256, 0, stream>>>(hB, W2r, W1r + 4096, hA, N);
    agg_bn_relu_kernel<<<ab, 256, 0, stream>>>(hA, row_ptr, col, gr + 64, br + 64, mr + 64, vr + 64, hB, N);

    gemm_pair_kernel<<<mb, 256, 0, stream>>>(hB, W2r + 4096, W1r + 8192, hA, N);
    agg_bn_relu_kernel<<<ab, 256, 0, stream>>>(hA, row_ptr, col, gr + 128, br + 128, mr + 128, vr + 128, hB, N);

    // ---- last layer: relu(h@W2_3) ----
    gemm_tiled_kernel<true><<<mb, 256, 0, stream>>>(hB, W2r + 8192, hA, N);

    // ---- pool (LDS-privatized partials) + head ----
    pool_partial_kernel<<<P, 256, 0, stream>>>(hA, batch, partial, pcnt, N);
    head_kernel<<<NGRAPH, 64, 0, stream>>>(partial, pcnt, P, lin1, lin2, b2, (float*)d_out);
}

// Round 7
// 662.620 us; speedup vs baseline: 1.7158x; 1.0415x over previous
//
#include <hip/hip_runtime.h>
#include <hip/hip_bf16.h>
#include <hip/hip_fp16.h>

#define HDIM 64
#define NGRAPH 128
#define NCLS 10
#define BN_EPS 1e-5f
#define SCAN_CHUNK 1024

// ---------------- CSR build ----------------

__global__ void count_kernel(const int* __restrict__ dst, int* __restrict__ deg, int E) {
    int e = blockIdx.x * blockDim.x + threadIdx.x;
    if (e < E) atomicAdd(&deg[dst[e]], 1);
}

__global__ void scan1_kernel(const int* __restrict__ deg, int* __restrict__ part, int N) {
    __shared__ int sh[256];
    int base = blockIdx.x * SCAN_CHUNK + threadIdx.x * 4;
    int s = 0;
#pragma unroll
    for (int i = 0; i < 4; i++) { int idx = base + i; if (idx < N) s += deg[idx]; }
    sh[threadIdx.x] = s; __syncthreads();
    for (int off = 128; off > 0; off >>= 1) {
        if (threadIdx.x < off) sh[threadIdx.x] += sh[threadIdx.x + off];
        __syncthreads();
    }
    if (threadIdx.x == 0) part[blockIdx.x] = sh[0];
}

__global__ void scan2_kernel(int* __restrict__ part, int nblk, int* __restrict__ row_ptr, int N, int E) {
    __shared__ int sh[256];
    int v = (threadIdx.x < nblk) ? part[threadIdx.x] : 0;
    sh[threadIdx.x] = v; __syncthreads();
    for (int off = 1; off < 256; off <<= 1) {
        int t = (threadIdx.x >= off) ? sh[threadIdx.x - off] : 0;
        __syncthreads();
        sh[threadIdx.x] += t;
        __syncthreads();
    }
    if (threadIdx.x < nblk) part[threadIdx.x] = sh[threadIdx.x] - v;  // exclusive
    if (threadIdx.x == 0) row_ptr[N] = E;
}

__global__ void scan3_kernel(const int* __restrict__ deg, const int* __restrict__ part,
                             int* __restrict__ row_ptr, int* __restrict__ cursor, int N) {
    __shared__ int sh[256];
    int tbase = blockIdx.x * SCAN_CHUNK + threadIdx.x * 4;
    int vals[4]; int s = 0;
#pragma unroll
    for (int i = 0; i < 4; i++) { int idx = tbase + i; vals[i] = (idx < N) ? deg[idx] : 0; s += vals[i]; }
    sh[threadIdx.x] = s; __syncthreads();
    for (int off = 1; off < 256; off <<= 1) {
        int t = (threadIdx.x >= off) ? sh[threadIdx.x - off] : 0;
        __syncthreads();
        sh[threadIdx.x] += t;
        __syncthreads();
    }
    int run = part[blockIdx.x] + sh[threadIdx.x] - s;  // exclusive prefix of this thread
#pragma unroll
    for (int i = 0; i < 4; i++) {
        int idx = tbase + i;
        if (idx < N) { row_ptr[idx] = run; cursor[idx] = run; run += vals[i]; }
    }
}

// ---------------- Fused: scatter (blocks [0,eb)) + layer-0 GEMM (blocks [eb,eb+mb)) ----
// GEMM output written fp16 (feeds the gather).

__global__ void __launch_bounds__(256) fused_scatter_gemm0_kernel(
        const int* __restrict__ src, const int* __restrict__ dst,
        int* __restrict__ cursor, int* __restrict__ col, int E, int eb,
        const float* __restrict__ X, const float* __restrict__ W,
        __half* __restrict__ Y, int N) {
    __shared__ float Xs[64 * 64];   // [k][n] for current K-half
    __shared__ float Ws[64 * 64];   // [k][j] for current K-half

    if ((int)blockIdx.x < eb) {
        int e = blockIdx.x * 256 + threadIdx.x;
        if (e < E) {
            int pos = atomicAdd(&cursor[dst[e]], 1);
            col[pos] = src[e];
        }
        return;
    }

    const int tid = threadIdx.x;
    const int base = (blockIdx.x - eb) * 64;
    const int ti = tid >> 4;
    const int tj = tid & 15;
    float4 acc[4];
#pragma unroll
    for (int a = 0; a < 4; a++) acc[a] = make_float4(0.f, 0.f, 0.f, 0.f);

    for (int kh = 0; kh < 2; kh++) {
        {
            const float4* Wv = reinterpret_cast<const float4*>(W + kh * 64 * 64);
            float4* Wsv = reinterpret_cast<float4*>(Ws);
            for (int i = tid; i < 1024; i += 256) Wsv[i] = Wv[i];
        }
        for (int i = tid; i < 1024; i += 256) {
            int r = i & 63;
            int c4 = i >> 6;
            int n = base + r;
            float4 v = make_float4(0.f, 0.f, 0.f, 0.f);
            if (n < N) v = *reinterpret_cast<const float4*>(X + (size_t)n * 128 + kh * 64 + c4 * 4);
            Xs[(c4 * 4 + 0) * 64 + r] = v.x;
            Xs[(c4 * 4 + 1) * 64 + r] = v.y;
            Xs[(c4 * 4 + 2) * 64 + r] = v.z;
            Xs[(c4 * 4 + 3) * 64 + r] = v.w;
        }
        __syncthreads();

#pragma unroll 4
        for (int k = 0; k < 64; k++) {
            float4 xv = *reinterpret_cast<const float4*>(&Xs[k * 64 + 4 * ti]);
            float4 wv = *reinterpret_cast<const float4*>(&Ws[k * 64 + 4 * tj]);
            acc[0].x += xv.x * wv.x; acc[0].y += xv.x * wv.y; acc[0].z += xv.x * wv.z; acc[0].w += xv.x * wv.w;
            acc[1].x += xv.y * wv.x; acc[1].y += xv.y * wv.y; acc[1].z += xv.y * wv.z; acc[1].w += xv.y * wv.w;
            acc[2].x += xv.z * wv.x; acc[2].y += xv.z * wv.y; acc[2].z += xv.z * wv.z; acc[2].w += xv.z * wv.w;
            acc[3].x += xv.w * wv.x; acc[3].y += xv.w * wv.y; acc[3].z += xv.w * wv.z; acc[3].w += xv.w * wv.w;
        }
        __syncthreads();
    }

#pragma unroll
    for (int a = 0; a < 4; a++) {
        int n = base + 4 * ti + a;
        if (n < N) {
            __half2* yp = reinterpret_cast<__half2*>(Y + (size_t)n * 64 + 4 * tj);
            yp[0] = __floats2half2_rn(acc[a].x, acc[a].y);
            yp[1] = __floats2half2_rn(acc[a].z, acc[a].w);
        }
    }
}

// ---------------- Tiled GEMM (fp32 in, fp32 out, in-place safe): Y = relu(X @ W) ----------------

template<bool RELU>
__global__ void __launch_bounds__(256) gemm_tiled_kernel(const float* __restrict__ X,
                                                         const float* __restrict__ W,
                                                         float* __restrict__ Y, int N) {
    __shared__ float Xs[64 * 64];   // [k][n]
    __shared__ float Ws[64 * 64];   // [k][j]
    const int tid = threadIdx.x;
    const int base = blockIdx.x * 64;

    {
        const float4* Wv = reinterpret_cast<const float4*>(W);
        float4* Wsv = reinterpret_cast<float4*>(Ws);
        for (int i = tid; i < 1024; i += 256) Wsv[i] = Wv[i];
    }
    for (int i = tid; i < 1024; i += 256) {
        int r = i & 63;
        int c4 = i >> 6;
        int n = base + r;
        float4 v = make_float4(0.f, 0.f, 0.f, 0.f);
        if (n < N) v = *reinterpret_cast<const float4*>(X + (size_t)n * 64 + c4 * 4);
        Xs[(c4 * 4 + 0) * 64 + r] = v.x;
        Xs[(c4 * 4 + 1) * 64 + r] = v.y;
        Xs[(c4 * 4 + 2) * 64 + r] = v.z;
        Xs[(c4 * 4 + 3) * 64 + r] = v.w;
    }
    __syncthreads();

    const int ti = tid >> 4;
    const int tj = tid & 15;
    float4 acc[4];
#pragma unroll
    for (int a = 0; a < 4; a++) acc[a] = make_float4(0.f, 0.f, 0.f, 0.f);

#pragma unroll 4
    for (int k = 0; k < 64; k++) {
        float4 xv = *reinterpret_cast<const float4*>(&Xs[k * 64 + 4 * ti]);
        float4 wv = *reinterpret_cast<const float4*>(&Ws[k * 64 + 4 * tj]);
        acc[0].x += xv.x * wv.x; acc[0].y += xv.x * wv.y; acc[0].z += xv.x * wv.z; acc[0].w += xv.x * wv.w;
        acc[1].x += xv.y * wv.x; acc[1].y += xv.y * wv.y; acc[1].z += xv.y * wv.z; acc[1].w += xv.y * wv.w;
        acc[2].x += xv.z * wv.x; acc[2].y += xv.z * wv.y; acc[2].z += xv.z * wv.z; acc[2].w += xv.z * wv.w;
        acc[3].x += xv.w * wv.x; acc[3].y += xv.w * wv.y; acc[3].z += xv.w * wv.z; acc[3].w += xv.w * wv.w;
    }

#pragma unroll
    for (int a = 0; a < 4; a++) {
        int n = base + 4 * ti + a;
        if (n < N) {
            float4 o = acc[a];
            if (RELU) {
                o.x = fmaxf(o.x, 0.f); o.y = fmaxf(o.y, 0.f);
                o.z = fmaxf(o.z, 0.f); o.w = fmaxf(o.w, 0.f);
            }
            *reinterpret_cast<float4*>(Y + (size_t)n * 64 + 4 * tj) = o;
        }
    }
}

// ---------------- Fused GEMM pair: Y16 = half( relu(H @ W2) @ W1n ) ----------------

__global__ void __launch_bounds__(256) gemm_pair_kernel(const float* __restrict__ H,
                                                        const float* __restrict__ W2,
                                                        const float* __restrict__ W1n,
                                                        __half* __restrict__ Y, int N) {
    __shared__ float Hs[64 * 64];   // stage1: [k][n]; reused as Z [n][j] for stage2
    __shared__ float W2s[64 * 64];  // [k][j]
    __shared__ float W1s[64 * 64];  // [k][j]
    const int tid = threadIdx.x;
    const int base = blockIdx.x * 64;

    {
        const float4* a = reinterpret_cast<const float4*>(W2);
        const float4* c = reinterpret_cast<const float4*>(W1n);
        float4* b = reinterpret_cast<float4*>(W2s);
        float4* d = reinterpret_cast<float4*>(W1s);
        for (int i = tid; i < 1024; i += 256) { b[i] = a[i]; d[i] = c[i]; }
    }
    for (int i = tid; i < 1024; i += 256) {
        int r = i & 63;
        int c4 = i >> 6;
        int n = base + r;
        float4 v = make_float4(0.f, 0.f, 0.f, 0.f);
        if (n < N) v = *reinterpret_cast<const float4*>(H + (size_t)n * 64 + c4 * 4);
        Hs[(c4 * 4 + 0) * 64 + r] = v.x;
        Hs[(c4 * 4 + 1) * 64 + r] = v.y;
        Hs[(c4 * 4 + 2) * 64 + r] = v.z;
        Hs[(c4 * 4 + 3) * 64 + r] = v.w;
    }
    __syncthreads();

    const int ti = tid >> 4;
    const int tj = tid & 15;
    float4 acc[4];
#pragma unroll
    for (int a = 0; a < 4; a++) acc[a] = make_float4(0.f, 0.f, 0.f, 0.f);

#pragma unroll 4
    for (int k = 0; k < 64; k++) {
        float4 xv = *reinterpret_cast<const float4*>(&Hs[k * 64 + 4 * ti]);
        float4 wv = *reinterpret_cast<const float4*>(&W2s[k * 64 + 4 * tj]);
        acc[0].x += xv.x * wv.x; acc[0].y += xv.x * wv.y; acc[0].z += xv.x * wv.z; acc[0].w += xv.x * wv.w;
        acc[1].x += xv.y * wv.x; acc[1].y += xv.y * wv.y; acc[1].z += xv.y * wv.z; acc[1].w += xv.y * wv.w;
        acc[2].x += xv.z * wv.x; acc[2].y += xv.z * wv.y; acc[2].z += xv.z * wv.z; acc[2].w += xv.z * wv.w;
        acc[3].x += xv.w * wv.x; acc[3].y += xv.w * wv.y; acc[3].z += xv.w * wv.z; acc[3].w += xv.w * wv.w;
    }
    __syncthreads();

#pragma unroll
    for (int a = 0; a < 4; a++) {
        float4 o = acc[a];
        o.x = fmaxf(o.x, 0.f); o.y = fmaxf(o.y, 0.f);
        o.z = fmaxf(o.z, 0.f); o.w = fmaxf(o.w, 0.f);
        *reinterpret_cast<float4*>(&Hs[(4 * ti + a) * 64 + 4 * tj]) = o;
    }
    __syncthreads();

    float4 acc2[4];
#pragma unroll
    for (int a = 0; a < 4; a++) acc2[a] = make_float4(0.f, 0.f, 0.f, 0.f);

#pragma unroll 4
    for (int k = 0; k < 64; k++) {
        float z0 = Hs[(4 * ti + 0) * 64 + k];
        float z1 = Hs[(4 * ti + 1) * 64 + k];
        float z2 = Hs[(4 * ti + 2) * 64 + k];
        float z3 = Hs[(4 * ti + 3) * 64 + k];
        float4 wv = *reinterpret_cast<const float4*>(&W1s[k * 64 + 4 * tj]);
        acc2[0].x += z0 * wv.x; acc2[0].y += z0 * wv.y; acc2[0].z += z0 * wv.z; acc2[0].w += z0 * wv.w;
        acc2[1].x += z1 * wv.x; acc2[1].y += z1 * wv.y; acc2[1].z += z1 * wv.z; acc2[1].w += z1 * wv.w;
        acc2[2].x += z2 * wv.x; acc2[2].y += z2 * wv.y; acc2[2].z += z2 * wv.z; acc2[2].w += z2 * wv.w;
        acc2[3].x += z3 * wv.x; acc2[3].y += z3 * wv.y; acc2[3].z += z3 * wv.z; acc2[3].w += z3 * wv.w;
    }

#pragma unroll
    for (int a = 0; a < 4; a++) {
        int n = base + 4 * ti + a;
        if (n < N) {
            __half2* yp = reinterpret_cast<__half2*>(Y + (size_t)n * 64 + 4 * tj);
            yp[0] = __floats2half2_rn(acc2[a].x, acc2[a].y);
            yp[1] = __floats2half2_rn(acc2[a].z, acc2[a].w);
        }
    }
}

// ---------------- Aggregation (pull, CSR, fp16 gather) + BatchNorm(eval) + ReLU ----------------
// 128B rows -> 2 cache lines per edge (was 4). Accumulate fp32; output fp32.

__global__ void agg_bn_relu_kernel(const __half* __restrict__ y, const int* __restrict__ rp,
                                   const int* __restrict__ col,
                                   const float* __restrict__ gam, const float* __restrict__ bet,
                                   const float* __restrict__ mu, const float* __restrict__ var,
                                   float* __restrict__ out, int N) {
    int wid = (blockIdx.x * blockDim.x + threadIdx.x) >> 6;
    int lane = threadIdx.x & 63;
    if (wid >= N) return;
    int beg = rp[wid], end = rp[wid + 1];
    float acc = __half2float(y[(size_t)wid * 64 + lane]);
    int e = beg;
    for (; e + 4 <= end; e += 4) {
        int s0 = col[e], s1 = col[e + 1], s2 = col[e + 2], s3 = col[e + 3];
        float a0 = __half2float(y[(size_t)s0 * 64 + lane]);
        float a1 = __half2float(y[(size_t)s1 * 64 + lane]);
        float a2 = __half2float(y[(size_t)s2 * 64 + lane]);
        float a3 = __half2float(y[(size_t)s3 * 64 + lane]);
        acc += a0 + a1 + a2 + a3;
    }
    for (; e < end; ++e) acc += __half2float(y[(size_t)col[e] * 64 + lane]);
    float sc = gam[lane] * rsqrtf(var[lane] + BN_EPS);
    float sh = bet[lane] - mu[lane] * sc;
    out[(size_t)wid * 64 + lane] = fmaxf(acc * sc + sh, 0.f);
}

// ---------------- Global mean pool, stage A: LDS-privatized partials ----------------

__global__ void __launch_bounds__(256) pool_partial_kernel(const float* __restrict__ h,
                                                           const int* __restrict__ batch,
                                                           float* __restrict__ partial,
                                                           int* __restrict__ pcnt, int N) {
    __shared__ float ls[NGRAPH * 64];
    __shared__ int lc[NGRAPH];
    for (int i = threadIdx.x; i < NGRAPH * 64; i += 256) ls[i] = 0.f;
    if (threadIdx.x < NGRAPH) lc[threadIdx.x] = 0;
    __syncthreads();
    int lane = threadIdx.x & 63;
    int gwave = blockIdx.x * 4 + (threadIdx.x >> 6);
    int nwaves = gridDim.x * 4;
#pragma unroll 4
    for (int n = gwave; n < N; n += nwaves) {
        int g = batch[n];
        atomicAdd(&ls[g * 64 + lane], h[(size_t)n * 64 + lane]);
        if (lane == 0) atomicAdd(&lc[g], 1);
    }
    __syncthreads();
    for (int i = threadIdx.x; i < NGRAPH * 64; i += 256)
        partial[(size_t)blockIdx.x * NGRAPH * 64 + i] = ls[i];
    if (threadIdx.x < NGRAPH) pcnt[blockIdx.x * NGRAPH + threadIdx.x] = lc[threadIdx.x];
}

// ---------------- Partial-reduce + MLP head + log_softmax (block per graph) ----------------

__global__ void head_kernel(const float* __restrict__ partial, const int* __restrict__ pcnt, int P,
                            const float* __restrict__ lin1, const float* __restrict__ lin2,
                            const float* __restrict__ b2, float* __restrict__ out) {
    int g = blockIdx.x;
    int j = threadIdx.x;  // 64 threads
    __shared__ float p[64];
    __shared__ float z1[64];
    __shared__ float z2[NCLS];
    __shared__ int csh[64];
    float s = 0.f;
    for (int b = 0; b < P; b++) s += partial[(size_t)b * NGRAPH * 64 + g * 64 + j];
    int c = 0;
    for (int b = j; b < P; b += 64) c += pcnt[b * NGRAPH + g];
    csh[j] = c; __syncthreads();
    if (j == 0) { int t = 0; for (int k = 0; k < 64; k++) t += csh[k]; csh[0] = t; }
    __syncthreads();
    float cnt = fmaxf((float)csh[0], 1.f);
    p[j] = s / cnt;
    __syncthreads();
    float a = 0.f;
#pragma unroll
    for (int k = 0; k < 64; k++) a += p[k] * lin1[k * 64 + j];
    z1[j] = fmaxf(a, 0.f);
    __syncthreads();
    if (j < NCLS) {
        float t = b2[j];
#pragma unroll
        for (int k = 0; k < 64; k++) t += z1[k] * lin2[k * NCLS + j];
        z2[j] = t;
    }
    __syncthreads();
    if (j < NCLS) {
        float mx = -1e30f;
#pragma unroll
        for (int c2 = 0; c2 < NCLS; c2++) mx = fmaxf(mx, z2[c2]);
        float se = 0.f;
#pragma unroll
        for (int c2 = 0; c2 < NCLS; c2++) se += expf(z2[c2] - mx);
        out[g * NCLS + j] = z2[j] - mx - logf(se);
    }
}

// ---------------- launch ----------------

extern "C" void kernel_launch(void* const* d_in, const int* in_sizes, int n_in,
                              void* d_out, int out_size, void* d_ws, size_t ws_size,
                              hipStream_t stream) {
    const float* x     = (const float*)d_in[0];
    const int*   ei    = (const int*)d_in[1];
    const int*   batch = (const int*)d_in[2];
    const float* W1_0  = (const float*)d_in[3];
    const float* g0    = (const float*)d_in[4];
    const float* b0    = (const float*)d_in[5];
    const float* m0    = (const float*)d_in[6];
    const float* v0    = (const float*)d_in[7];
    const float* W2_0  = (const float*)d_in[8];
    const float* W1r   = (const float*)d_in[9];
    const float* gr    = (const float*)d_in[10];
    const float* br    = (const float*)d_in[11];
    const float* mr    = (const float*)d_in[12];
    const float* vr    = (const float*)d_in[13];
    const float* W2r   = (const float*)d_in[14];
    const float* lin1  = (const float*)d_in[15];
    const float* lin2  = (const float*)d_in[16];
    const float* b2    = (const float*)d_in[17];

    const int N = in_sizes[0] / 128;   // 100000
    const int E = in_sizes[1] / 2;     // 1000000
    const int* src = ei;
    const int* dst = ei + E;

    // ---- workspace carve (256B aligned) ----
    char* p = (char*)d_ws;
    auto alloc = [&](size_t bytes) -> char* {
        char* r = p;
        p += (bytes + 255) & ~(size_t)255;
        return r;
    };
    int*    deg     = (int*)alloc((size_t)N * 4);
    int*    row_ptr = (int*)alloc((size_t)(N + 1) * 4);
    int*    cursor  = (int*)alloc((size_t)N * 4);
    int*    col     = (int*)alloc((size_t)E * 4);
    int*    part    = (int*)alloc(256 * 4);
    float*  hA      = (float*)alloc((size_t)N * 64 * 4);
    __half* y16     = (__half*)alloc((size_t)N * 64 * 2);
    size_t used = (size_t)(p - (char*)d_ws);
    size_t per_block = ((size_t)NGRAPH * 64 * 4) + ((size_t)NGRAPH * 4) + 512;
    size_t remain = (ws_size > used) ? (ws_size - used) : 0;
    int P = (int)(remain / per_block);
    if (P > 256) P = 256;
    if (P < 1) P = 1;
    float* partial = (float*)alloc((size_t)P * NGRAPH * 64 * 4);
    int*   pcnt    = (int*)alloc((size_t)P * NGRAPH * 4);
    (void)n_in; (void)out_size;

    hipMemsetAsync(deg, 0, (size_t)N * 4, stream);

    // ---- CSR build ----
    int eb = (E + 255) / 256;
    count_kernel<<<eb, 256, 0, stream>>>(dst, deg, E);
    int nblk = (N + SCAN_CHUNK - 1) / SCAN_CHUNK;
    scan1_kernel<<<nblk, 256, 0, stream>>>(deg, part, N);
    scan2_kernel<<<1, 256, 0, stream>>>(part, nblk, row_ptr, N, E);
    scan3_kernel<<<nblk, 256, 0, stream>>>(deg, part, row_ptr, cursor, N);

    int mb = (N + 63) / 64;
    int ab = (N * 64 + 255) / 256;

    // ---- fused: CSR scatter || layer-0 GEMM (fp16 out) ----
    fused_scatter_gemm0_kernel<<<eb + mb, 256, 0, stream>>>(src, dst, cursor, col, E, eb,
                                                            x, W1_0, y16, N);
    agg_bn_relu_kernel<<<ab, 256, 0, stream>>>(y16, row_ptr, col, g0, b0, m0, v0, hA, N);

    // ---- fused pairs: relu(h@W2_i) @ W1_{i+1} (fp16 out), then agg+bn+relu ----
    gemm_pair_kernel<<<mb, 256, 0, stream>>>(hA, W2_0, W1r, y16, N);
    agg_bn_relu_kernel<<<ab, 256, 0, stream>>>(y16, row_ptr, col, gr, br, mr, vr, hA, N);

    gemm_pair_kernel<<<mb, 256, 0, stream>>>(hA, W2r, W1r + 4096, y16, N);
    agg_bn_relu_kernel<<<ab, 256, 0, stream>>>(y16, row_ptr, col, gr + 64, br + 64, mr + 64, vr + 64, hA, N);

    gemm_pair_kernel<<<mb, 256, 0, stream>>>(hA, W2r + 4096, W1r + 8192, y16, N);
    agg_bn_relu_kernel<<<ab, 256, 0, stream>>>(y16, row_ptr, col, gr + 128, br + 128, mr + 128, vr + 128, hA, N);

    // ---- last layer: relu(h@W2_3), in-place (block-local rows staged in LDS first) ----
    gemm_tiled_kernel<true><<<mb, 256, 0, stream>>>(hA, W2r + 8192, hA, N);

    // ---- pool (LDS-privatized partials) + head ----
    pool_partial_kernel<<<P, 256, 0, stream>>>(hA, batch, partial, pcnt, N);
    head_kernel<<<NGRAPH, 64, 0, stream>>>(partial, pcnt, P, lin1, lin2, b2, (float*)d_out);
}

// Round 8
// 644.687 us; speedup vs baseline: 1.7635x; 1.0278x over previous
//
#include <hip/hip_runtime.h>
#include <hip/hip_bf16.h>
#include <hip/hip_fp16.h>

#define HDIM 64
#define NGRAPH 128
#define NCLS 10
#define BN_EPS 1e-5f
#define SCAN_CHUNK 1024

// ---------------- CSR build ----------------

__global__ void count_kernel(const int* __restrict__ dst, int* __restrict__ deg, int E) {
    int e = blockIdx.x * blockDim.x + threadIdx.x;
    if (e < E) atomicAdd(&deg[dst[e]], 1);
}

__global__ void scan1_kernel(const int* __restrict__ deg, int* __restrict__ part, int N) {
    __shared__ int sh[256];
    int base = blockIdx.x * SCAN_CHUNK + threadIdx.x * 4;
    int s = 0;
#pragma unroll
    for (int i = 0; i < 4; i++) { int idx = base + i; if (idx < N) s += deg[idx]; }
    sh[threadIdx.x] = s; __syncthreads();
    for (int off = 128; off > 0; off >>= 1) {
        if (threadIdx.x < off) sh[threadIdx.x] += sh[threadIdx.x + off];
        __syncthreads();
    }
    if (threadIdx.x == 0) part[blockIdx.x] = sh[0];
}

__global__ void scan2_kernel(int* __restrict__ part, int nblk, int* __restrict__ row_ptr, int N, int E) {
    __shared__ int sh[256];
    int v = (threadIdx.x < nblk) ? part[threadIdx.x] : 0;
    sh[threadIdx.x] = v; __syncthreads();
    for (int off = 1; off < 256; off <<= 1) {
        int t = (threadIdx.x >= off) ? sh[threadIdx.x - off] : 0;
        __syncthreads();
        sh[threadIdx.x] += t;
        __syncthreads();
    }
    if (threadIdx.x < nblk) part[threadIdx.x] = sh[threadIdx.x] - v;  // exclusive
    if (threadIdx.x == 0) row_ptr[N] = E;
}

__global__ void scan3_kernel(const int* __restrict__ deg, const int* __restrict__ part,
                             int* __restrict__ row_ptr, int* __restrict__ cursor, int N) {
    __shared__ int sh[256];
    int tbase = blockIdx.x * SCAN_CHUNK + threadIdx.x * 4;
    int vals[4]; int s = 0;
#pragma unroll
    for (int i = 0; i < 4; i++) { int idx = tbase + i; vals[i] = (idx < N) ? deg[idx] : 0; s += vals[i]; }
    sh[threadIdx.x] = s; __syncthreads();
    for (int off = 1; off < 256; off <<= 1) {
        int t = (threadIdx.x >= off) ? sh[threadIdx.x - off] : 0;
        __syncthreads();
        sh[threadIdx.x] += t;
        __syncthreads();
    }
    int run = part[blockIdx.x] + sh[threadIdx.x] - s;  // exclusive prefix of this thread
#pragma unroll
    for (int i = 0; i < 4; i++) {
        int idx = tbase + i;
        if (idx < N) { row_ptr[idx] = run; cursor[idx] = run; run += vals[i]; }
    }
}

// ---------------- Fused: scatter (blocks [0,eb)) + layer-0 GEMM (blocks [eb,eb+mb)) ----

__global__ void __launch_bounds__(256) fused_scatter_gemm0_kernel(
        const int* __restrict__ src, const int* __restrict__ dst,
        int* __restrict__ cursor, int* __restrict__ col, int E, int eb,
        const float* __restrict__ X, const float* __restrict__ W,
        __half* __restrict__ Y, int N) {
    __shared__ float Xs[64 * 64];   // [k][n] for current K-half
    __shared__ float Ws[64 * 64];   // [k][j] for current K-half

    if ((int)blockIdx.x < eb) {
        int e = blockIdx.x * 256 + threadIdx.x;
        if (e < E) {
            int pos = atomicAdd(&cursor[dst[e]], 1);
            col[pos] = src[e];
        }
        return;
    }

    const int tid = threadIdx.x;
    const int base = (blockIdx.x - eb) * 64;
    const int ti = tid >> 4;
    const int tj = tid & 15;
    float4 acc[4];
#pragma unroll
    for (int a = 0; a < 4; a++) acc[a] = make_float4(0.f, 0.f, 0.f, 0.f);

    for (int kh = 0; kh < 2; kh++) {
        {
            const float4* Wv = reinterpret_cast<const float4*>(W + kh * 64 * 64);
            float4* Wsv = reinterpret_cast<float4*>(Ws);
            for (int i = tid; i < 1024; i += 256) Wsv[i] = Wv[i];
        }
        for (int i = tid; i < 1024; i += 256) {
            int r = i & 63;
            int c4 = i >> 6;
            int n = base + r;
            float4 v = make_float4(0.f, 0.f, 0.f, 0.f);
            if (n < N) v = *reinterpret_cast<const float4*>(X + (size_t)n * 128 + kh * 64 + c4 * 4);
            Xs[(c4 * 4 + 0) * 64 + r] = v.x;
            Xs[(c4 * 4 + 1) * 64 + r] = v.y;
            Xs[(c4 * 4 + 2) * 64 + r] = v.z;
            Xs[(c4 * 4 + 3) * 64 + r] = v.w;
        }
        __syncthreads();

#pragma unroll 4
        for (int k = 0; k < 64; k++) {
            float4 xv = *reinterpret_cast<const float4*>(&Xs[k * 64 + 4 * ti]);
            float4 wv = *reinterpret_cast<const float4*>(&Ws[k * 64 + 4 * tj]);
            acc[0].x += xv.x * wv.x; acc[0].y += xv.x * wv.y; acc[0].z += xv.x * wv.z; acc[0].w += xv.x * wv.w;
            acc[1].x += xv.y * wv.x; acc[1].y += xv.y * wv.y; acc[1].z += xv.y * wv.z; acc[1].w += xv.y * wv.w;
            acc[2].x += xv.z * wv.x; acc[2].y += xv.z * wv.y; acc[2].z += xv.z * wv.z; acc[2].w += xv.z * wv.w;
            acc[3].x += xv.w * wv.x; acc[3].y += xv.w * wv.y; acc[3].z += xv.w * wv.z; acc[3].w += xv.w * wv.w;
        }
        __syncthreads();
    }

#pragma unroll
    for (int a = 0; a < 4; a++) {
        int n = base + 4 * ti + a;
        if (n < N) {
            __half2* yp = reinterpret_cast<__half2*>(Y + (size_t)n * 64 + 4 * tj);
            yp[0] = __floats2half2_rn(acc[a].x, acc[a].y);
            yp[1] = __floats2half2_rn(acc[a].z, acc[a].w);
        }
    }
}

// ---------------- Tiled GEMM (fp32 in, fp32 out, in-place safe): Y = relu(X @ W) ----------------

template<bool RELU>
__global__ void __launch_bounds__(256) gemm_tiled_kernel(const float* __restrict__ X,
                                                         const float* __restrict__ W,
                                                         float* __restrict__ Y, int N) {
    __shared__ float Xs[64 * 64];   // [k][n]
    __shared__ float Ws[64 * 64];   // [k][j]
    const int tid = threadIdx.x;
    const int base = blockIdx.x * 64;

    {
        const float4* Wv = reinterpret_cast<const float4*>(W);
        float4* Wsv = reinterpret_cast<float4*>(Ws);
        for (int i = tid; i < 1024; i += 256) Wsv[i] = Wv[i];
    }
    for (int i = tid; i < 1024; i += 256) {
        int r = i & 63;
        int c4 = i >> 6;
        int n = base + r;
        float4 v = make_float4(0.f, 0.f, 0.f, 0.f);
        if (n < N) v = *reinterpret_cast<const float4*>(X + (size_t)n * 64 + c4 * 4);
        Xs[(c4 * 4 + 0) * 64 + r] = v.x;
        Xs[(c4 * 4 + 1) * 64 + r] = v.y;
        Xs[(c4 * 4 + 2) * 64 + r] = v.z;
        Xs[(c4 * 4 + 3) * 64 + r] = v.w;
    }
    __syncthreads();

    const int ti = tid >> 4;
    const int tj = tid & 15;
    float4 acc[4];
#pragma unroll
    for (int a = 0; a < 4; a++) acc[a] = make_float4(0.f, 0.f, 0.f, 0.f);

#pragma unroll 4
    for (int k = 0; k < 64; k++) {
        float4 xv = *reinterpret_cast<const float4*>(&Xs[k * 64 + 4 * ti]);
        float4 wv = *reinterpret_cast<const float4*>(&Ws[k * 64 + 4 * tj]);
        acc[0].x += xv.x * wv.x; acc[0].y += xv.x * wv.y; acc[0].z += xv.x * wv.z; acc[0].w += xv.x * wv.w;
        acc[1].x += xv.y * wv.x; acc[1].y += xv.y * wv.y; acc[1].z += xv.y * wv.z; acc[1].w += xv.y * wv.w;
        acc[2].x += xv.z * wv.x; acc[2].y += xv.z * wv.y; acc[2].z += xv.z * wv.z; acc[2].w += xv.z * wv.w;
        acc[3].x += xv.w * wv.x; acc[3].y += xv.w * wv.y; acc[3].z += xv.w * wv.z; acc[3].w += xv.w * wv.w;
    }

#pragma unroll
    for (int a = 0; a < 4; a++) {
        int n = base + 4 * ti + a;
        if (n < N) {
            float4 o = acc[a];
            if (RELU) {
                o.x = fmaxf(o.x, 0.f); o.y = fmaxf(o.y, 0.f);
                o.z = fmaxf(o.z, 0.f); o.w = fmaxf(o.w, 0.f);
            }
            *reinterpret_cast<float4*>(Y + (size_t)n * 64 + 4 * tj) = o;
        }
    }
}

// ---------------- Fused GEMM pair: Y16 = half( relu(H @ W2) @ W1n ) ----------------

__global__ void __launch_bounds__(256) gemm_pair_kernel(const float* __restrict__ H,
                                                        const float* __restrict__ W2,
                                                        const float* __restrict__ W1n,
                                                        __half* __restrict__ Y, int N) {
    __shared__ float Hs[64 * 64];   // stage1: [k][n]; reused as Z [n][j] for stage2
    __shared__ float W2s[64 * 64];  // [k][j]
    __shared__ float W1s[64 * 64];  // [k][j]
    const int tid = threadIdx.x;
    const int base = blockIdx.x * 64;

    {
        const float4* a = reinterpret_cast<const float4*>(W2);
        const float4* c = reinterpret_cast<const float4*>(W1n);
        float4* b = reinterpret_cast<float4*>(W2s);
        float4* d = reinterpret_cast<float4*>(W1s);
        for (int i = tid; i < 1024; i += 256) { b[i] = a[i]; d[i] = c[i]; }
    }
    for (int i = tid; i < 1024; i += 256) {
        int r = i & 63;
        int c4 = i >> 6;
        int n = base + r;
        float4 v = make_float4(0.f, 0.f, 0.f, 0.f);
        if (n < N) v = *reinterpret_cast<const float4*>(H + (size_t)n * 64 + c4 * 4);
        Hs[(c4 * 4 + 0) * 64 + r] = v.x;
        Hs[(c4 * 4 + 1) * 64 + r] = v.y;
        Hs[(c4 * 4 + 2) * 64 + r] = v.z;
        Hs[(c4 * 4 + 3) * 64 + r] = v.w;
    }
    __syncthreads();

    const int ti = tid >> 4;
    const int tj = tid & 15;
    float4 acc[4];
#pragma unroll
    for (int a = 0; a < 4; a++) acc[a] = make_float4(0.f, 0.f, 0.f, 0.f);

#pragma unroll 4
    for (int k = 0; k < 64; k++) {
        float4 xv = *reinterpret_cast<const float4*>(&Hs[k * 64 + 4 * ti]);
        float4 wv = *reinterpret_cast<const float4*>(&W2s[k * 64 + 4 * tj]);
        acc[0].x += xv.x * wv.x; acc[0].y += xv.x * wv.y; acc[0].z += xv.x * wv.z; acc[0].w += xv.x * wv.w;
        acc[1].x += xv.y * wv.x; acc[1].y += xv.y * wv.y; acc[1].z += xv.y * wv.z; acc[1].w += xv.y * wv.w;
        acc[2].x += xv.z * wv.x; acc[2].y += xv.z * wv.y; acc[2].z += xv.z * wv.z; acc[2].w += xv.z * wv.w;
        acc[3].x += xv.w * wv.x; acc[3].y += xv.w * wv.y; acc[3].z += xv.w * wv.z; acc[3].w += xv.w * wv.w;
    }
    __syncthreads();

#pragma unroll
    for (int a = 0; a < 4; a++) {
        float4 o = acc[a];
        o.x = fmaxf(o.x, 0.f); o.y = fmaxf(o.y, 0.f);
        o.z = fmaxf(o.z, 0.f); o.w = fmaxf(o.w, 0.f);
        *reinterpret_cast<float4*>(&Hs[(4 * ti + a) * 64 + 4 * tj]) = o;
    }
    __syncthreads();

    float4 acc2[4];
#pragma unroll
    for (int a = 0; a < 4; a++) acc2[a] = make_float4(0.f, 0.f, 0.f, 0.f);

#pragma unroll 4
    for (int k = 0; k < 64; k++) {
        float z0 = Hs[(4 * ti + 0) * 64 + k];
        float z1 = Hs[(4 * ti + 1) * 64 + k];
        float z2 = Hs[(4 * ti + 2) * 64 + k];
        float z3 = Hs[(4 * ti + 3) * 64 + k];
        float4 wv = *reinterpret_cast<const float4*>(&W1s[k * 64 + 4 * tj]);
        acc2[0].x += z0 * wv.x; acc2[0].y += z0 * wv.y; acc2[0].z += z0 * wv.z; acc2[0].w += z0 * wv.w;
        acc2[1].x += z1 * wv.x; acc2[1].y += z1 * wv.y; acc2[1].z += z1 * wv.z; acc2[1].w += z1 * wv.w;
        acc2[2].x += z2 * wv.x; acc2[2].y += z2 * wv.y; acc2[2].z += z2 * wv.z; acc2[2].w += z2 * wv.w;
        acc2[3].x += z3 * wv.x; acc2[3].y += z3 * wv.y; acc2[3].z += z3 * wv.z; acc2[3].w += z3 * wv.w;
    }

#pragma unroll
    for (int a = 0; a < 4; a++) {
        int n = base + 4 * ti + a;
        if (n < N) {
            __half2* yp = reinterpret_cast<__half2*>(Y + (size_t)n * 64 + 4 * tj);
            yp[0] = __floats2half2_rn(acc2[a].x, acc2[a].y);
            yp[1] = __floats2half2_rn(acc2[a].z, acc2[a].w);
        }
    }
}

// ---------------- Aggregation (pull, CSR, fp16 gather, dual-edge) + BN + ReLU ----------------
// Wave per node. Lane-group 0 (lanes 0-31) takes even edges, group 1 odd edges;
// each lane loads __half2 (4B) so a group covers the 128B row in one request.
// 4-deep unroll per group = 8 rows in flight per wave (2x the old MLP).
// Groups' fp32 partials combine via one shfl; group 0 does BN+ReLU and float2 store.

__global__ void agg_bn_relu_kernel(const __half* __restrict__ y, const int* __restrict__ rp,
                                   const int* __restrict__ col,
                                   const float* __restrict__ gam, const float* __restrict__ bet,
                                   const float* __restrict__ mu, const float* __restrict__ var,
                                   float* __restrict__ out, int N) {
    int wid = (blockIdx.x * blockDim.x + threadIdx.x) >> 6;
    int lane = threadIdx.x & 63;
    if (wid >= N) return;
    int grp = lane >> 5;      // 0: even edges, 1: odd edges
    int fl  = lane & 31;      // feature-pair index (features 2fl, 2fl+1)
    int beg = rp[wid], end = rp[wid + 1];

    float2 acc = make_float2(0.f, 0.f);
    if (grp == 0) {  // self row
        float2 f = __half22float2(*reinterpret_cast<const __half2*>(y + (size_t)wid * 64 + fl * 2));
        acc.x += f.x; acc.y += f.y;
    }
    int e = beg + grp;
    for (; e + 6 < end; e += 8) {  // this group: e, e+2, e+4, e+6
        int s0 = col[e], s1 = col[e + 2], s2 = col[e + 4], s3 = col[e + 6];
        float2 a0 = __half22float2(*reinterpret_cast<const __half2*>(y + (size_t)s0 * 64 + fl * 2));
        float2 a1 = __half22float2(*reinterpret_cast<const __half2*>(y + (size_t)s1 * 64 + fl * 2));
        float2 a2 = __half22float2(*reinterpret_cast<const __half2*>(y + (size_t)s2 * 64 + fl * 2));
        float2 a3 = __half22float2(*reinterpret_cast<const __half2*>(y + (size_t)s3 * 64 + fl * 2));
        acc.x += a0.x + a1.x + a2.x + a3.x;
        acc.y += a0.y + a1.y + a2.y + a3.y;
    }
    for (; e < end; e += 2) {
        float2 a = __half22float2(*reinterpret_cast<const __half2*>(y + (size_t)col[e] * 64 + fl * 2));
        acc.x += a.x; acc.y += a.y;
    }

    // combine the two lane-groups (lane f gets lane f+32's partial)
    acc.x += __shfl_down(acc.x, 32);
    acc.y += __shfl_down(acc.y, 32);

    if (grp == 0) {
        int f0 = fl * 2, f1 = f0 + 1;
        float sc0 = gam[f0] * rsqrtf(var[f0] + BN_EPS);
        float sc1 = gam[f1] * rsqrtf(var[f1] + BN_EPS);
        float2 o;
        o.x = fmaxf(acc.x * sc0 + (bet[f0] - mu[f0] * sc0), 0.f);
        o.y = fmaxf(acc.y * sc1 + (bet[f1] - mu[f1] * sc1), 0.f);
        *reinterpret_cast<float2*>(out + (size_t)wid * 64 + f0) = o;
    }
}

// ---------------- Global mean pool, stage A: LDS-privatized partials ----------------

__global__ void __launch_bounds__(256) pool_partial_kernel(const float* __restrict__ h,
                                                           const int* __restrict__ batch,
                                                           float* __restrict__ partial,
                                                           int* __restrict__ pcnt, int N) {
    __shared__ float ls[NGRAPH * 64];
    __shared__ int lc[NGRAPH];
    for (int i = threadIdx.x; i < NGRAPH * 64; i += 256) ls[i] = 0.f;
    if (threadIdx.x < NGRAPH) lc[threadIdx.x] = 0;
    __syncthreads();
    int lane = threadIdx.x & 63;
    int gwave = blockIdx.x * 4 + (threadIdx.x >> 6);
    int nwaves = gridDim.x * 4;
#pragma unroll 4
    for (int n = gwave; n < N; n += nwaves) {
        int g = batch[n];
        atomicAdd(&ls[g * 64 + lane], h[(size_t)n * 64 + lane]);
        if (lane == 0) atomicAdd(&lc[g], 1);
    }
    __syncthreads();
    for (int i = threadIdx.x; i < NGRAPH * 64; i += 256)
        partial[(size_t)blockIdx.x * NGRAPH * 64 + i] = ls[i];
    if (threadIdx.x < NGRAPH) pcnt[blockIdx.x * NGRAPH + threadIdx.x] = lc[threadIdx.x];
}

// ---------------- Partial-reduce + MLP head + log_softmax (block per graph) ----------------

__global__ void head_kernel(const float* __restrict__ partial, const int* __restrict__ pcnt, int P,
                            const float* __restrict__ lin1, const float* __restrict__ lin2,
                            const float* __restrict__ b2, float* __restrict__ out) {
    int g = blockIdx.x;
    int j = threadIdx.x;  // 64 threads
    __shared__ float p[64];
    __shared__ float z1[64];
    __shared__ float z2[NCLS];
    __shared__ int csh[64];
    float s = 0.f;
    for (int b = 0; b < P; b++) s += partial[(size_t)b * NGRAPH * 64 + g * 64 + j];
    int c = 0;
    for (int b = j; b < P; b += 64) c += pcnt[b * NGRAPH + g];
    csh[j] = c; __syncthreads();
    if (j == 0) { int t = 0; for (int k = 0; k < 64; k++) t += csh[k]; csh[0] = t; }
    __syncthreads();
    float cnt = fmaxf((float)csh[0], 1.f);
    p[j] = s / cnt;
    __syncthreads();
    float a = 0.f;
#pragma unroll
    for (int k = 0; k < 64; k++) a += p[k] * lin1[k * 64 + j];
    z1[j] = fmaxf(a, 0.f);
    __syncthreads();
    if (j < NCLS) {
        float t = b2[j];
#pragma unroll
        for (int k = 0; k < 64; k++) t += z1[k] * lin2[k * NCLS + j];
        z2[j] = t;
    }
    __syncthreads();
    if (j < NCLS) {
        float mx = -1e30f;
#pragma unroll
        for (int c2 = 0; c2 < NCLS; c2++) mx = fmaxf(mx, z2[c2]);
        float se = 0.f;
#pragma unroll
        for (int c2 = 0; c2 < NCLS; c2++) se += expf(z2[c2] - mx);
        out[g * NCLS + j] = z2[j] - mx - logf(se);
    }
}

// ---------------- launch ----------------

extern "C" void kernel_launch(void* const* d_in, const int* in_sizes, int n_in,
                              void* d_out, int out_size, void* d_ws, size_t ws_size,
                              hipStream_t stream) {
    const float* x     = (const float*)d_in[0];
    const int*   ei    = (const int*)d_in[1];
    const int*   batch = (const int*)d_in[2];
    const float* W1_0  = (const float*)d_in[3];
    const float* g0    = (const float*)d_in[4];
    const float* b0    = (const float*)d_in[5];
    const float* m0    = (const float*)d_in[6];
    const float* v0    = (const float*)d_in[7];
    const float* W2_0  = (const float*)d_in[8];
    const float* W1r   = (const float*)d_in[9];
    const float* gr    = (const float*)d_in[10];
    const float* br    = (const float*)d_in[11];
    const float* mr    = (const float*)d_in[12];
    const float* vr    = (const float*)d_in[13];
    const float* W2r   = (const float*)d_in[14];
    const float* lin1  = (const float*)d_in[15];
    const float* lin2  = (const float*)d_in[16];
    const float* b2    = (const float*)d_in[17];

    const int N = in_sizes[0] / 128;   // 100000
    const int E = in_sizes[1] / 2;     // 1000000
    const int* src = ei;
    const int* dst = ei + E;

    // ---- workspace carve (256B aligned) ----
    char* p = (char*)d_ws;
    auto alloc = [&](size_t bytes) -> char* {
        char* r = p;
        p += (bytes + 255) & ~(size_t)255;
        return r;
    };
    int*    deg     = (int*)alloc((size_t)N * 4);
    int*    row_ptr = (int*)alloc((size_t)(N + 1) * 4);
    int*    cursor  = (int*)alloc((size_t)N * 4);
    int*    col     = (int*)alloc((size_t)E * 4);
    int*    part    = (int*)alloc(256 * 4);
    float*  hA      = (float*)alloc((size_t)N * 64 * 4);
    __half* y16     = (__half*)alloc((size_t)N * 64 * 2);
    size_t used = (size_t)(p - (char*)d_ws);
    size_t per_block = ((size_t)NGRAPH * 64 * 4) + ((size_t)NGRAPH * 4) + 512;
    size_t remain = (ws_size > used) ? (ws_size - used) : 0;
    int P = (int)(remain / per_block);
    if (P > 256) P = 256;
    if (P < 1) P = 1;
    float* partial = (float*)alloc((size_t)P * NGRAPH * 64 * 4);
    int*   pcnt    = (int*)alloc((size_t)P * NGRAPH * 4);
    (void)n_in; (void)out_size;

    hipMemsetAsync(deg, 0, (size_t)N * 4, stream);

    // ---- CSR build ----
    int eb = (E + 255) / 256;
    count_kernel<<<eb, 256, 0, stream>>>(dst, deg, E);
    int nblk = (N + SCAN_CHUNK - 1) / SCAN_CHUNK;
    scan1_kernel<<<nblk, 256, 0, stream>>>(deg, part, N);
    scan2_kernel<<<1, 256, 0, stream>>>(part, nblk, row_ptr, N, E);
    scan3_kernel<<<nblk, 256, 0, stream>>>(deg, part, row_ptr, cursor, N);

    int mb = (N + 63) / 64;
    int ab = (N * 64 + 255) / 256;

    // ---- fused: CSR scatter || layer-0 GEMM (fp16 out) ----
    fused_scatter_gemm0_kernel<<<eb + mb, 256, 0, stream>>>(src, dst, cursor, col, E, eb,
                                                            x, W1_0, y16, N);
    agg_bn_relu_kernel<<<ab, 256, 0, stream>>>(y16, row_ptr, col, g0, b0, m0, v0, hA, N);

    // ---- fused pairs: relu(h@W2_i) @ W1_{i+1} (fp16 out), then agg+bn+relu ----
    gemm_pair_kernel<<<mb, 256, 0, stream>>>(hA, W2_0, W1r, y16, N);
    agg_bn_relu_kernel<<<ab, 256, 0, stream>>>(y16, row_ptr, col, gr, br, mr, vr, hA, N);

    gemm_pair_kernel<<<mb, 256, 0, stream>>>(hA, W2r, W1r + 4096, y16, N);
    agg_bn_relu_kernel<<<ab, 256, 0, stream>>>(y16, row_ptr, col, gr + 64, br + 64, mr + 64, vr + 64, hA, N);

    gemm_pair_kernel<<<mb, 256, 0, stream>>>(hA, W2r + 4096, W1r + 8192, y16, N);
    agg_bn_relu_kernel<<<ab, 256, 0, stream>>>(y16, row_ptr, col, gr + 128, br + 128, mr + 128, vr + 128, hA, N);

    // ---- last layer: relu(h@W2_3), in-place ----
    gemm_tiled_kernel<true><<<mb, 256, 0, stream>>>(hA, W2r + 8192, hA, N);

    // ---- pool (LDS-privatized partials) + head ----
    pool_partial_kernel<<<P, 256, 0, stream>>>(hA, batch, partial, pcnt, N);
    head_kernel<<<NGRAPH, 64, 0, stream>>>(partial, pcnt, P, lin1, lin2, b2, (float*)d_out);
}

// Round 10
// 593.188 us; speedup vs baseline: 1.9166x; 1.0868x over previous
//
#include <hip/hip_runtime.h>
#include <hip/hip_bf16.h>
#include <hip/hip_fp16.h>

#define HDIM 64
#define NGRAPH 128
#define NCLS 10
#define BN_EPS 1e-5f
#define SCAN_CHUNK 1024
#define LDH 72   // padded LDS row stride in halves (144B -> no 16-way conflicts)

typedef _Float16 h16;
typedef __attribute__((ext_vector_type(8))) _Float16 f16x8;
typedef __attribute__((ext_vector_type(4))) float f32x4;

// ---------------- CSR build ----------------

__global__ void count_kernel(const int* __restrict__ dst, int* __restrict__ deg, int E) {
    int e = blockIdx.x * blockDim.x + threadIdx.x;
    if (e < E) atomicAdd(&deg[dst[e]], 1);
}

__global__ void scan1_kernel(const int* __restrict__ deg, int* __restrict__ part, int N) {
    __shared__ int sh[256];
    int base = blockIdx.x * SCAN_CHUNK + threadIdx.x * 4;
    int s = 0;
#pragma unroll
    for (int i = 0; i < 4; i++) { int idx = base + i; if (idx < N) s += deg[idx]; }
    sh[threadIdx.x] = s; __syncthreads();
    for (int off = 128; off > 0; off >>= 1) {
        if (threadIdx.x < off) sh[threadIdx.x] += sh[threadIdx.x + off];
        __syncthreads();
    }
    if (threadIdx.x == 0) part[blockIdx.x] = sh[0];
}

__global__ void scan2_kernel(int* __restrict__ part, int nblk, int* __restrict__ row_ptr, int N, int E) {
    __shared__ int sh[256];
    int v = (threadIdx.x < nblk) ? part[threadIdx.x] : 0;
    sh[threadIdx.x] = v; __syncthreads();
    for (int off = 1; off < 256; off <<= 1) {
        int t = (threadIdx.x >= off) ? sh[threadIdx.x - off] : 0;
        __syncthreads();
        sh[threadIdx.x] += t;
        __syncthreads();
    }
    if (threadIdx.x < nblk) part[threadIdx.x] = sh[threadIdx.x] - v;  // exclusive
    if (threadIdx.x == 0) row_ptr[N] = E;
}

__global__ void scan3_kernel(const int* __restrict__ deg, const int* __restrict__ part,
                             int* __restrict__ row_ptr, int* __restrict__ cursor, int N) {
    __shared__ int sh[256];
    int tbase = blockIdx.x * SCAN_CHUNK + threadIdx.x * 4;
    int vals[4]; int s = 0;
#pragma unroll
    for (int i = 0; i < 4; i++) { int idx = tbase + i; vals[i] = (idx < N) ? deg[idx] : 0; s += vals[i]; }
    sh[threadIdx.x] = s; __syncthreads();
    for (int off = 1; off < 256; off <<= 1) {
        int t = (threadIdx.x >= off) ? sh[threadIdx.x - off] : 0;
        __syncthreads();
        sh[threadIdx.x] += t;
        __syncthreads();
    }
    int run = part[blockIdx.x] + sh[threadIdx.x] - s;
#pragma unroll
    for (int i = 0; i < 4; i++) {
        int idx = tbase + i;
        if (idx < N) { row_ptr[idx] = run; cursor[idx] = run; run += vals[i]; }
    }
}

// ---------------- Weight prep: transpose+convert 7 64x64 fp32 -> fp16 [j][k] ----------------
// order: 0:W2_0  1..3:W2r[0..2]  4..6:W1r[0..2]

__global__ void prep_weights_kernel(const float* __restrict__ W2_0,
                                    const float* __restrict__ W2r,
                                    const float* __restrict__ W1r,
                                    h16* __restrict__ wt) {
    int b = blockIdx.x;
    const float* src = (b == 0) ? W2_0 : (b <= 3) ? W2r + (size_t)(b - 1) * 4096
                                                  : W1r + (size_t)(b - 4) * 4096;
    h16* dst = wt + (size_t)b * 4096;
    for (int i = threadIdx.x; i < 4096; i += 256) {
        int k = i >> 6, j = i & 63;
        dst[j * 64 + k] = (h16)src[k * 64 + j];
    }
}

// ---------------- Fused: scatter (blocks [0,eb)) + layer-0 GEMM fp32 (blocks [eb,eb+mb)) ----

__global__ void __launch_bounds__(256) fused_scatter_gemm0_kernel(
        const int* __restrict__ src, const int* __restrict__ dst,
        int* __restrict__ cursor, int* __restrict__ col, int E, int eb,
        const float* __restrict__ X, const float* __restrict__ W,
        __half* __restrict__ Y, int N) {
    __shared__ float Xs[64 * 64];
    __shared__ float Ws[64 * 64];

    if ((int)blockIdx.x < eb) {
        int e = blockIdx.x * 256 + threadIdx.x;
        if (e < E) {
            int pos = atomicAdd(&cursor[dst[e]], 1);
            col[pos] = src[e];
        }
        return;
    }

    const int tid = threadIdx.x;
    const int base = (blockIdx.x - eb) * 64;
    const int ti = tid >> 4;
    const int tj = tid & 15;
    float4 acc[4];
#pragma unroll
    for (int a = 0; a < 4; a++) acc[a] = make_float4(0.f, 0.f, 0.f, 0.f);

    for (int kh = 0; kh < 2; kh++) {
        {
            const float4* Wv = reinterpret_cast<const float4*>(W + kh * 64 * 64);
            float4* Wsv = reinterpret_cast<float4*>(Ws);
            for (int i = tid; i < 1024; i += 256) Wsv[i] = Wv[i];
        }
        for (int i = tid; i < 1024; i += 256) {
            int r = i & 63;
            int c4 = i >> 6;
            int n = base + r;
            float4 v = make_float4(0.f, 0.f, 0.f, 0.f);
            if (n < N) v = *reinterpret_cast<const float4*>(X + (size_t)n * 128 + kh * 64 + c4 * 4);
            Xs[(c4 * 4 + 0) * 64 + r] = v.x;
            Xs[(c4 * 4 + 1) * 64 + r] = v.y;
            Xs[(c4 * 4 + 2) * 64 + r] = v.z;
            Xs[(c4 * 4 + 3) * 64 + r] = v.w;
        }
        __syncthreads();

#pragma unroll 4
        for (int k = 0; k < 64; k++) {
            float4 xv = *reinterpret_cast<const float4*>(&Xs[k * 64 + 4 * ti]);
            float4 wv = *reinterpret_cast<const float4*>(&Ws[k * 64 + 4 * tj]);
            acc[0].x += xv.x * wv.x; acc[0].y += xv.x * wv.y; acc[0].z += xv.x * wv.z; acc[0].w += xv.x * wv.w;
            acc[1].x += xv.y * wv.x; acc[1].y += xv.y * wv.y; acc[1].z += xv.y * wv.z; acc[1].w += xv.y * wv.w;
            acc[2].x += xv.z * wv.x; acc[2].y += xv.z * wv.y; acc[2].z += xv.z * wv.z; acc[2].w += xv.z * wv.w;
            acc[3].x += xv.w * wv.x; acc[3].y += xv.w * wv.y; acc[3].z += xv.w * wv.z; acc[3].w += xv.w * wv.w;
        }
        __syncthreads();
    }

#pragma unroll
    for (int a = 0; a < 4; a++) {
        int n = base + 4 * ti + a;
        if (n < N) {
            __half2* yp = reinterpret_cast<__half2*>(Y + (size_t)n * 64 + 4 * tj);
            yp[0] = __floats2half2_rn(acc[a].x, acc[a].y);
            yp[1] = __floats2half2_rn(acc[a].z, acc[a].w);
        }
    }
}

// ---------------- MFMA GEMM pair: Y16 = half( relu(H @ W2) @ W1 ) ----------------
// 64x64 tile, 4 waves; wave w owns output rows 16w..16w+15 wave-privately through
// BOTH stages (A rows == D rows), Z round-trips through the wave's own Xs rows.
// A-frag: lane l -> row=l&15, k=(l>>4)*8..+7. D: col=l&15, row=(l>>4)*4+reg.

__global__ void __launch_bounds__(256) gemm_pair_mfma(const float* __restrict__ H,
                                                      const h16* __restrict__ Wt2,
                                                      const h16* __restrict__ Wt1,
                                                      __half* __restrict__ Y, int N) {
    __shared__ h16 Xs[64 * LDH];
    __shared__ h16 W2s[64 * LDH];
    __shared__ h16 W1s[64 * LDH];
    const int tid = threadIdx.x;
    const int base = blockIdx.x * 64;

    // stage X: fp32 -> fp16, [n][64] padded to LDH
#pragma unroll
    for (int it = 0; it < 4; ++it) {
        int idx = it * 256 + tid;      // 1024 float4 chunks
        int row = idx >> 4, q = idx & 15;
        float4 v = make_float4(0.f, 0.f, 0.f, 0.f);
        int n = base + row;
        if (n < N) v = *reinterpret_cast<const float4*>(H + (size_t)n * 64 + q * 4);
        h16* d = &Xs[row * LDH + q * 4];
        d[0] = (h16)v.x; d[1] = (h16)v.y; d[2] = (h16)v.z; d[3] = (h16)v.w;
    }
    // stage weights (already [j][k] fp16 in global)
#pragma unroll
    for (int it = 0; it < 2; ++it) {
        int idx = it * 256 + tid;      // 512 chunks of 8 halves
        int row = idx >> 3, q = idx & 7;
        *reinterpret_cast<f16x8*>(&W2s[row * LDH + q * 8]) =
            *reinterpret_cast<const f16x8*>(Wt2 + row * 64 + q * 8);
        *reinterpret_cast<f16x8*>(&W1s[row * LDH + q * 8]) =
            *reinterpret_cast<const f16x8*>(Wt1 + row * 64 + q * 8);
    }
    __syncthreads();

    const int w  = tid >> 6;
    const int l  = tid & 63;
    const int lr = l & 15;
    const int lk = l >> 4;

    // ---- stage 1: Z = relu(X @ W2) ----
    f16x8 a0 = *reinterpret_cast<const f16x8*>(&Xs[(16 * w + lr) * LDH + lk * 8]);
    f16x8 a1 = *reinterpret_cast<const f16x8*>(&Xs[(16 * w + lr) * LDH + 32 + lk * 8]);
    f32x4 acc[4];
#pragma unroll
    for (int t = 0; t < 4; ++t) {
        f16x8 b0 = *reinterpret_cast<const f16x8*>(&W2s[(16 * t + lr) * LDH + lk * 8]);
        f16x8 b1 = *reinterpret_cast<const f16x8*>(&W2s[(16 * t + lr) * LDH + 32 + lk * 8]);
        f32x4 c = {0.f, 0.f, 0.f, 0.f};
        c = __builtin_amdgcn_mfma_f32_16x16x32_f16(a0, b0, c, 0, 0, 0);
        c = __builtin_amdgcn_mfma_f32_16x16x32_f16(a1, b1, c, 0, 0, 0);
        acc[t] = c;
    }
    // relu -> fp16 -> the wave's own Xs rows
#pragma unroll
    for (int t = 0; t < 4; ++t)
#pragma unroll
        for (int r = 0; r < 4; ++r)
            Xs[(16 * w + lk * 4 + r) * LDH + 16 * t + lr] = (h16)fmaxf(acc[t][r], 0.f);
    __syncthreads();

    // ---- stage 2: Y = Z @ W1 ----
    f16x8 z0 = *reinterpret_cast<const f16x8*>(&Xs[(16 * w + lr) * LDH + lk * 8]);
    f16x8 z1 = *reinterpret_cast<const f16x8*>(&Xs[(16 * w + lr) * LDH + 32 + lk * 8]);
    f32x4 acc2[4];
#pragma unroll
    for (int t = 0; t < 4; ++t) {
        f16x8 b0 = *reinterpret_cast<const f16x8*>(&W1s[(16 * t + lr) * LDH + lk * 8]);
        f16x8 b1 = *reinterpret_cast<const f16x8*>(&W1s[(16 * t + lr) * LDH + 32 + lk * 8]);
        f32x4 c = {0.f, 0.f, 0.f, 0.f};
        c = __builtin_amdgcn_mfma_f32_16x16x32_f16(z0, b0, c, 0, 0, 0);
        c = __builtin_amdgcn_mfma_f32_16x16x32_f16(z1, b1, c, 0, 0, 0);
        acc2[t] = c;
    }
    // stage output into W2s (fully consumed), then coalesced copy-out
#pragma unroll
    for (int t = 0; t < 4; ++t)
#pragma unroll
        for (int r = 0; r < 4; ++r)
            W2s[(16 * w + lk * 4 + r) * LDH + 16 * t + lr] = (h16)acc2[t][r];
    __syncthreads();

#pragma unroll
    for (int it = 0; it < 2; ++it) {
        int idx = it * 256 + tid;
        int row = idx >> 3, q = idx & 7;
        int n = base + row;
        if (n < N)
            *reinterpret_cast<f16x8*>(reinterpret_cast<h16*>(Y) + (size_t)n * 64 + q * 8) =
                *reinterpret_cast<const f16x8*>(&W2s[row * LDH + q * 8]);
    }
}

// ---------------- MFMA last GEMM: Yf32 = relu(H @ W2_3), in-place safe ----------------

__global__ void __launch_bounds__(256) gemm_last_mfma(const float* __restrict__ H,
                                                      const h16* __restrict__ Wt,
                                                      float* __restrict__ Y, int N) {
    __shared__ h16 Xs[64 * LDH];
    __shared__ h16 Ws[64 * LDH];
    __shared__ float Zf[64 * 68];
    const int tid = threadIdx.x;
    const int base = blockIdx.x * 64;

#pragma unroll
    for (int it = 0; it < 4; ++it) {
        int idx = it * 256 + tid;
        int row = idx >> 4, q = idx & 15;
        float4 v = make_float4(0.f, 0.f, 0.f, 0.f);
        int n = base + row;
        if (n < N) v = *reinterpret_cast<const float4*>(H + (size_t)n * 64 + q * 4);
        h16* d = &Xs[row * LDH + q * 4];
        d[0] = (h16)v.x; d[1] = (h16)v.y; d[2] = (h16)v.z; d[3] = (h16)v.w;
    }
#pragma unroll
    for (int it = 0; it < 2; ++it) {
        int idx = it * 256 + tid;
        int row = idx >> 3, q = idx & 7;
        *reinterpret_cast<f16x8*>(&Ws[row * LDH + q * 8]) =
            *reinterpret_cast<const f16x8*>(Wt + row * 64 + q * 8);
    }
    __syncthreads();

    const int w  = tid >> 6;
    const int l  = tid & 63;
    const int lr = l & 15;
    const int lk = l >> 4;

    f16x8 a0 = *reinterpret_cast<const f16x8*>(&Xs[(16 * w + lr) * LDH + lk * 8]);
    f16x8 a1 = *reinterpret_cast<const f16x8*>(&Xs[(16 * w + lr) * LDH + 32 + lk * 8]);
#pragma unroll
    for (int t = 0; t < 4; ++t) {
        f16x8 b0 = *reinterpret_cast<const f16x8*>(&Ws[(16 * t + lr) * LDH + lk * 8]);
        f16x8 b1 = *reinterpret_cast<const f16x8*>(&Ws[(16 * t + lr) * LDH + 32 + lk * 8]);
        f32x4 c = {0.f, 0.f, 0.f, 0.f};
        c = __builtin_amdgcn_mfma_f32_16x16x32_f16(a0, b0, c, 0, 0, 0);
        c = __builtin_amdgcn_mfma_f32_16x16x32_f16(a1, b1, c, 0, 0, 0);
#pragma unroll
        for (int r = 0; r < 4; ++r)
            Zf[(16 * w + lk * 4 + r) * 68 + 16 * t + lr] = fmaxf(c[r], 0.f);
    }
    __syncthreads();

#pragma unroll
    for (int it = 0; it < 4; ++it) {
        int idx = it * 256 + tid;
        int row = idx >> 4, q = idx & 15;
        int n = base + row;
        if (n < N)
            *reinterpret_cast<float4*>(Y + (size_t)n * 64 + q * 4) =
                *reinterpret_cast<const float4*>(&Zf[row * 68 + q * 4]);
    }
}

// ---------------- Aggregation (pull, CSR, fp16 gather, dual-edge) + BN + ReLU ----------------

__global__ void agg_bn_relu_kernel(const __half* __restrict__ y, const int* __restrict__ rp,
                                   const int* __restrict__ col,
                                   const float* __restrict__ gam, const float* __restrict__ bet,
                                   const float* __restrict__ mu, const float* __restrict__ var,
                                   float* __restrict__ out, int N) {
    int wid = (blockIdx.x * blockDim.x + threadIdx.x) >> 6;
    int lane = threadIdx.x & 63;
    if (wid >= N) return;
    int grp = lane >> 5;
    int fl  = lane & 31;
    int beg = rp[wid], end = rp[wid + 1];

    float2 acc = make_float2(0.f, 0.f);
    if (grp == 0) {
        float2 f = __half22float2(*reinterpret_cast<const __half2*>(y + (size_t)wid * 64 + fl * 2));
        acc.x += f.x; acc.y += f.y;
    }
    int e = beg + grp;
    for (; e + 6 < end; e += 8) {
        int s0 = col[e], s1 = col[e + 2], s2 = col[e + 4], s3 = col[e + 6];
        float2 a0 = __half22float2(*reinterpret_cast<const __half2*>(y + (size_t)s0 * 64 + fl * 2));
        float2 a1 = __half22float2(*reinterpret_cast<const __half2*>(y + (size_t)s1 * 64 + fl * 2));
        float2 a2 = __half22float2(*reinterpret_cast<const __half2*>(y + (size_t)s2 * 64 + fl * 2));
        float2 a3 = __half22float2(*reinterpret_cast<const __half2*>(y + (size_t)s3 * 64 + fl * 2));
        acc.x += a0.x + a1.x + a2.x + a3.x;
        acc.y += a0.y + a1.y + a2.y + a3.y;
    }
    for (; e < end; e += 2) {
        float2 a = __half22float2(*reinterpret_cast<const __half2*>(y + (size_t)col[e] * 64 + fl * 2));
        acc.x += a.x; acc.y += a.y;
    }

    acc.x += __shfl_down(acc.x, 32);
    acc.y += __shfl_down(acc.y, 32);

    if (grp == 0) {
        int f0 = fl * 2, f1 = f0 + 1;
        float sc0 = gam[f0] * rsqrtf(var[f0] + BN_EPS);
        float sc1 = gam[f1] * rsqrtf(var[f1] + BN_EPS);
        float2 o;
        o.x = fmaxf(acc.x * sc0 + (bet[f0] - mu[f0] * sc0), 0.f);
        o.y = fmaxf(acc.y * sc1 + (bet[f1] - mu[f1] * sc1), 0.f);
        *reinterpret_cast<float2*>(out + (size_t)wid * 64 + f0) = o;
    }
}

// ---------------- Global mean pool, stage A: LDS-privatized partials ----------------

__global__ void __launch_bounds__(256) pool_partial_kernel(const float* __restrict__ h,
                                                           const int* __restrict__ batch,
                                                           float* __restrict__ partial,
                                                           int* __restrict__ pcnt, int N) {
    __shared__ float ls[NGRAPH * 64];
    __shared__ int lc[NGRAPH];
    for (int i = threadIdx.x; i < NGRAPH * 64; i += 256) ls[i] = 0.f;
    if (threadIdx.x < NGRAPH) lc[threadIdx.x] = 0;
    __syncthreads();
    int lane = threadIdx.x & 63;
    int gwave = blockIdx.x * 4 + (threadIdx.x >> 6);
    int nwaves = gridDim.x * 4;
#pragma unroll 4
    for (int n = gwave; n < N; n += nwaves) {
        int g = batch[n];
        atomicAdd(&ls[g * 64 + lane], h[(size_t)n * 64 + lane]);
        if (lane == 0) atomicAdd(&lc[g], 1);
    }
    __syncthreads();
    for (int i = threadIdx.x; i < NGRAPH * 64; i += 256)
        partial[(size_t)blockIdx.x * NGRAPH * 64 + i] = ls[i];
    if (threadIdx.x < NGRAPH) pcnt[blockIdx.x * NGRAPH + threadIdx.x] = lc[threadIdx.x];
}

// ---------------- Partial-reduce + MLP head + log_softmax (block per graph) ----------------

__global__ void head_kernel(const float* __restrict__ partial, const int* __restrict__ pcnt, int P,
                            const float* __restrict__ lin1, const float* __restrict__ lin2,
                            const float* __restrict__ b2, float* __restrict__ out) {
    int g = blockIdx.x;
    int j = threadIdx.x;
    __shared__ float p[64];
    __shared__ float z1[64];
    __shared__ float z2[NCLS];
    __shared__ int csh[64];
    float s = 0.f;
    for (int b = 0; b < P; b++) s += partial[(size_t)b * NGRAPH * 64 + g * 64 + j];
    int c = 0;
    for (int b = j; b < P; b += 64) c += pcnt[b * NGRAPH + g];
    csh[j] = c; __syncthreads();
    if (j == 0) { int t = 0; for (int k = 0; k < 64; k++) t += csh[k]; csh[0] = t; }
    __syncthreads();
    float cnt = fmaxf((float)csh[0], 1.f);
    p[j] = s / cnt;
    __syncthreads();
    float a = 0.f;
#pragma unroll
    for (int k = 0; k < 64; k++) a += p[k] * lin1[k * 64 + j];
    z1[j] = fmaxf(a, 0.f);
    __syncthreads();
    if (j < NCLS) {
        float t = b2[j];
#pragma unroll
        for (int k = 0; k < 64; k++) t += z1[k] * lin2[k * NCLS + j];
        z2[j] = t;
    }
    __syncthreads();
    if (j < NCLS) {
        float mx = -1e30f;
#pragma unroll
        for (int c2 = 0; c2 < NCLS; c2++) mx = fmaxf(mx, z2[c2]);
        float se = 0.f;
#pragma unroll
        for (int c2 = 0; c2 < NCLS; c2++) se += expf(z2[c2] - mx);
        out[g * NCLS + j] = z2[j] - mx - logf(se);
    }
}

// ---------------- launch ----------------

extern "C" void kernel_launch(void* const* d_in, const int* in_sizes, int n_in,
                              void* d_out, int out_size, void* d_ws, size_t ws_size,
                              hipStream_t stream) {
    const float* x     = (const float*)d_in[0];
    const int*   ei    = (const int*)d_in[1];
    const int*   batch = (const int*)d_in[2];
    const float* W1_0  = (const float*)d_in[3];
    const float* g0    = (const float*)d_in[4];
    const float* b0    = (const float*)d_in[5];
    const float* m0    = (const float*)d_in[6];
    const float* v0    = (const float*)d_in[7];
    const float* W2_0  = (const float*)d_in[8];
    const float* W1r   = (const float*)d_in[9];
    const float* gr    = (const float*)d_in[10];
    const float* br    = (const float*)d_in[11];
    const float* mr    = (const float*)d_in[12];
    const float* vr    = (const float*)d_in[13];
    const float* W2r   = (const float*)d_in[14];
    const float* lin1  = (const float*)d_in[15];
    const float* lin2  = (const float*)d_in[16];
    const float* b2    = (const float*)d_in[17];

    const int N = in_sizes[0] / 128;   // 100000
    const int E = in_sizes[1] / 2;     // 1000000
    const int* src = ei;
    const int* dst = ei + E;

    // ---- workspace carve (256B aligned) ----
    char* p = (char*)d_ws;
    auto alloc = [&](size_t bytes) -> char* {
        char* r = p;
        p += (bytes + 255) & ~(size_t)255;
        return r;
    };
    int*    deg     = (int*)alloc((size_t)N * 4);
    int*    row_ptr = (int*)alloc((size_t)(N + 1) * 4);
    int*    cursor  = (int*)alloc((size_t)N * 4);
    int*    col     = (int*)alloc((size_t)E * 4);
    int*    part    = (int*)alloc(256 * 4);
    float*  hA      = (float*)alloc((size_t)N * 64 * 4);
    __half* y16     = (__half*)alloc((size_t)N * 64 * 2);
    h16*    wt      = (h16*)alloc((size_t)7 * 4096 * 2);
    size_t used = (size_t)(p - (char*)d_ws);
    size_t per_block = ((size_t)NGRAPH * 64 * 4) + ((size_t)NGRAPH * 4) + 512;
    size_t remain = (ws_size > used) ? (ws_size - used) : 0;
    int P = (int)(remain / per_block);
    if (P > 256) P = 256;
    if (P < 1) P = 1;
    float* partial = (float*)alloc((size_t)P * NGRAPH * 64 * 4);
    int*   pcnt    = (int*)alloc((size_t)P * NGRAPH * 4);
    (void)n_in; (void)out_size;

    hipMemsetAsync(deg, 0, (size_t)N * 4, stream);

    // ---- weight prep + CSR build ----
    prep_weights_kernel<<<7, 256, 0, stream>>>(W2_0, W2r, W1r, wt);
    int eb = (E + 255) / 256;
    count_kernel<<<eb, 256, 0, stream>>>(dst, deg, E);
    int nblk = (N + SCAN_CHUNK - 1) / SCAN_CHUNK;
    scan1_kernel<<<nblk, 256, 0, stream>>>(deg, part, N);
    scan2_kernel<<<1, 256, 0, stream>>>(part, nblk, row_ptr, N, E);
    scan3_kernel<<<nblk, 256, 0, stream>>>(deg, part, row_ptr, cursor, N);

    int mb = (N + 63) / 64;
    int ab = (N * 64 + 255) / 256;

    // ---- fused: CSR scatter || layer-0 GEMM (fp16 out) ----
    fused_scatter_gemm0_kernel<<<eb + mb, 256, 0, stream>>>(src, dst, cursor, col, E, eb,
                                                            x, W1_0, y16, N);
    agg_bn_relu_kernel<<<ab, 256, 0, stream>>>(y16, row_ptr, col, g0, b0, m0, v0, hA, N);

    // ---- MFMA fused pairs: relu(h@W2_i) @ W1_{i+1} (fp16 out), then agg+bn+relu ----
    gemm_pair_mfma<<<mb, 256, 0, stream>>>(hA, wt + 0 * 4096, wt + 4 * 4096, y16, N);
    agg_bn_relu_kernel<<<ab, 256, 0, stream>>>(y16, row_ptr, col, gr, br, mr, vr, hA, N);

    gemm_pair_mfma<<<mb, 256, 0, stream>>>(hA, wt + 1 * 4096, wt + 5 * 4096, y16, N);
    agg_bn_relu_kernel<<<ab, 256, 0, stream>>>(y16, row_ptr, col, gr + 64, br + 64, mr + 64, vr + 64, hA, N);

    gemm_pair_mfma<<<mb, 256, 0, stream>>>(hA, wt + 2 * 4096, wt + 6 * 4096, y16, N);
    agg_bn_relu_kernel<<<ab, 256, 0, stream>>>(y16, row_ptr, col, gr + 128, br + 128, mr + 128, vr + 128, hA, N);

    // ---- last layer: relu(h@W2_3) via MFMA, in-place ----
    gemm_last_mfma<<<mb, 256, 0, stream>>>(hA, wt + 3 * 4096, hA, N);

    // ---- pool (LDS-privatized partials) + head ----
    pool_partial_kernel<<<P, 256, 0, stream>>>(hA, batch, partial, pcnt, N);
    head_kernel<<<NGRAPH, 64, 0, stream>>>(partial, pcnt, P, lin1, lin2, b2, (float*)d_out);
}